// Round 1
// baseline (5274.737 us; speedup 1.0000x reference)
//
#include <hip/hip_runtime.h>
#include <hip/hip_bf16.h>
#include <cmath>

#define TK 12

// ---------------------------------------------------------------------------
// Generic f32 tiled GEMM: C = [relu]( Aeff @ W + bias )  [+= if ACC]
//   AMODE 0: Aeff = A1;  1: Aeff = A1 + A2;  2: Aeff = A1 * A2
// BM=BN=64, BK=16, 256 threads, 4x4 micro-tile.
// ---------------------------------------------------------------------------
template<bool RELU, int AMODE, bool ACC>
__global__ __launch_bounds__(256) void gemm_bias(
    const float* __restrict__ A1, const float* __restrict__ A2,
    const float* __restrict__ W, const float* __restrict__ bias,
    float* __restrict__ C, int M, int N, int K)
{
    __shared__ float As[16][68];   // [k][row]
    __shared__ float Ws[16][68];   // [k][col]
    const int tid = threadIdx.x;
    const int bx = blockIdx.x, by = blockIdx.y;
    const int tx = tid & 15, ty = tid >> 4;
    const int ar = tid >> 2, akq = tid & 3;    // A tile load: row 0..63, k-quad 0..3
    const int wr = tid >> 4, wcq = tid & 15;   // W tile load: k 0..15, col-quad 0..15

    const float* a1p = A1 + (size_t)(by*64 + ar)*K + akq*4;
    const float* a2p = (AMODE != 0) ? (A2 + (size_t)(by*64 + ar)*K + akq*4) : nullptr;
    const float* wp  = W  + (size_t)wr*N + bx*64 + wcq*4;

    float acc[4][4];
    #pragma unroll
    for (int i = 0; i < 4; ++i)
        #pragma unroll
        for (int j = 0; j < 4; ++j) acc[i][j] = 0.f;

    for (int kt = 0; kt < K; kt += 16) {
        float4 a = *(const float4*)(a1p + kt);
        if (AMODE == 1) {
            float4 b = *(const float4*)(a2p + kt);
            a.x += b.x; a.y += b.y; a.z += b.z; a.w += b.w;
        } else if (AMODE == 2) {
            float4 b = *(const float4*)(a2p + kt);
            a.x *= b.x; a.y *= b.y; a.z *= b.z; a.w *= b.w;
        }
        float4 w = *(const float4*)(wp + (size_t)kt * N);
        __syncthreads();
        As[akq*4+0][ar] = a.x;
        As[akq*4+1][ar] = a.y;
        As[akq*4+2][ar] = a.z;
        As[akq*4+3][ar] = a.w;
        *(float4*)&Ws[wr][wcq*4] = w;
        __syncthreads();
        #pragma unroll
        for (int kk = 0; kk < 16; ++kk) {
            float4 av = *(const float4*)&As[kk][ty*4];
            float4 bv = *(const float4*)&Ws[kk][tx*4];
            acc[0][0] += av.x*bv.x; acc[0][1] += av.x*bv.y; acc[0][2] += av.x*bv.z; acc[0][3] += av.x*bv.w;
            acc[1][0] += av.y*bv.x; acc[1][1] += av.y*bv.y; acc[1][2] += av.y*bv.z; acc[1][3] += av.y*bv.w;
            acc[2][0] += av.z*bv.x; acc[2][1] += av.z*bv.y; acc[2][2] += av.z*bv.z; acc[2][3] += av.z*bv.w;
            acc[3][0] += av.w*bv.x; acc[3][1] += av.w*bv.y; acc[3][2] += av.w*bv.z; acc[3][3] += av.w*bv.w;
        }
    }
    const int row0 = by*64 + ty*4, col0 = bx*64 + tx*4;
    const float b0 = bias[col0+0], b1 = bias[col0+1], b2 = bias[col0+2], b3 = bias[col0+3];
    #pragma unroll
    for (int ii = 0; ii < 4; ++ii) {
        float* cp = C + (size_t)(row0+ii)*N + col0;
        float v0 = acc[ii][0] + b0;
        float v1 = acc[ii][1] + b1;
        float v2 = acc[ii][2] + b2;
        float v3 = acc[ii][3] + b3;
        if (RELU) {
            v0 = fmaxf(v0, 0.f); v1 = fmaxf(v1, 0.f);
            v2 = fmaxf(v2, 0.f); v3 = fmaxf(v3, 0.f);
        }
        if (ACC) {
            cp[0] += v0; cp[1] += v1; cp[2] += v2; cp[3] += v3;
        } else {
            cp[0] = v0; cp[1] = v1; cp[2] = v2; cp[3] = v3;
        }
    }
}

// ---------------------------------------------------------------------------
// Fused score + top-k (partial). Grid (4, 192), 256 threads (4 waves).
// Block = 64 rows x 3072-column chunk; wave handles 768 columns; lane owns row.
// e_h tile (scaled by 1/16) staged in 64KB LDS as [quad][row] float4.
// Per-lane register top-12, intra-block merge -> pv/pi[row][blockIdx.x][12].
// ---------------------------------------------------------------------------
__global__ __launch_bounds__(256) void score_topk(
    const float* __restrict__ e_h, const float* __restrict__ e_t,
    float* __restrict__ pv, int* __restrict__ pi)
{
    __shared__ float smem[64 * 256];          // 64 KB, reused for merge
    float4* ehs4 = (float4*)smem;
    const int tid  = threadIdx.x;
    const int lane = tid & 63;
    const int wave = tid >> 6;
    const int row0 = blockIdx.y * 64;

    // stage scaled e_h tile: global [row][k] -> LDS [quad][row]
    #pragma unroll
    for (int l = 0; l < 16; ++l) {
        int idx = l * 256 + tid;
        int r = idx >> 6;
        int q = idx & 63;
        float4 v = *(const float4*)(e_h + (size_t)(row0 + r) * 256 + q * 4);
        v.x *= 0.0625f; v.y *= 0.0625f; v.z *= 0.0625f; v.w *= 0.0625f;
        ehs4[q * 64 + r] = v;
    }
    __syncthreads();

    float tv[TK]; int ti[TK];
    #pragma unroll
    for (int j = 0; j < TK; ++j) { tv[j] = -__builtin_inff(); ti[j] = 0x7fffffff; }
    float vmin = -__builtin_inff();

    auto insert = [&](float s, int c) {
        if (s > vmin) {
            bool done = false;
            #pragma unroll
            for (int j = 0; j < TK; ++j) {
                if (!done && tv[j] == vmin) { tv[j] = s; ti[j] = c; done = true; }
            }
            float m = tv[0];
            #pragma unroll
            for (int j = 1; j < TK; ++j) m = fminf(m, tv[j]);
            vmin = m;
        }
    };

    int cb = (blockIdx.x * 4 + wave) * 768;
    cb = __builtin_amdgcn_readfirstlane(cb);

    for (int it = 0; it < 192; ++it) {
        const int c0 = cb + it * 4;
        const float4* b0 = (const float4*)(e_t + (size_t)c0 * 256);
        const float4* b1 = b0 + 64;
        const float4* b2 = b0 + 128;
        const float4* b3 = b0 + 192;
        float s0 = 0.f, s1 = 0.f, s2 = 0.f, s3 = 0.f;
        #pragma unroll 8
        for (int q = 0; q < 64; ++q) {
            float4 a  = ehs4[q * 64 + lane];
            float4 x0 = b0[q];
            float4 x1 = b1[q];
            float4 x2 = b2[q];
            float4 x3 = b3[q];
            s0 += a.x*x0.x + a.y*x0.y + a.z*x0.z + a.w*x0.w;
            s1 += a.x*x1.x + a.y*x1.y + a.z*x1.z + a.w*x1.w;
            s2 += a.x*x2.x + a.y*x2.y + a.z*x2.z + a.w*x2.w;
            s3 += a.x*x3.x + a.y*x3.y + a.z*x3.z + a.w*x3.w;
        }
        insert(s0, c0 + 0);
        insert(s1, c0 + 1);
        insert(s2, c0 + 2);
        insert(s3, c0 + 3);
    }

    // intra-block merge: 4 wave-partials -> 1 top-12 per row
    __syncthreads();                      // ehs no longer needed
    float* pvL = smem;                    // [48][64]
    int*   piL = (int*)(smem + 48 * 64);  // [48][64]
    #pragma unroll
    for (int j = 0; j < TK; ++j) {
        pvL[(wave * TK + j) * 64 + lane] = tv[j];
        piL[(wave * TK + j) * 64 + lane] = ti[j];
    }
    __syncthreads();
    if (wave == 0) {
        const int row = row0 + lane;
        float* opv = pv + ((size_t)row * 4 + blockIdx.x) * TK;
        int*   opi = pi + ((size_t)row * 4 + blockIdx.x) * TK;
        float lastV = __builtin_inff(); int lastI = -1;
        #pragma unroll 1
        for (int j = 0; j < TK; ++j) {
            float bv = -__builtin_inff(); int bi = 0x7fffffff;
            for (int t = 0; t < 48; ++t) {
                float v  = pvL[t * 64 + lane];
                int   ix = piL[t * 64 + lane];
                bool elig   = (v < lastV) || (v == lastV && ix > lastI);
                bool better = (v > bv)    || (v == bv    && ix < bi);
                if (elig && better) { bv = v; bi = ix; }
            }
            opv[j] = bv; opi[j] = bi; lastV = bv; lastI = bi;
        }
    }
}

// ---------------------------------------------------------------------------
// Per-row tail: merge 4 block-partials -> final top-12, softmax, gather,
// gate/ka attention, e_Nh.  One wave per row, 4 rows per block.
// ---------------------------------------------------------------------------
__global__ __launch_bounds__(256) void tail_kernel(
    const float* __restrict__ e_h, const float* __restrict__ e_t,
    const float* __restrict__ pv, const int* __restrict__ pi,
    float* __restrict__ e_Nh)
{
    const int lane = threadIdx.x & 63;
    const int wave = threadIdx.x >> 6;
    const int row  = blockIdx.x * 4 + wave;

    const float* pvr = pv + (size_t)row * 48;
    const int*   pir = pi + (size_t)row * 48;

    // all 64 lanes redundantly compute the same merge (uniform loads)
    float tv[TK]; int ti[TK];
    float lastV = __builtin_inff(); int lastI = -1;
    #pragma unroll
    for (int j = 0; j < TK; ++j) {
        float bv = -__builtin_inff(); int bi = 0x7fffffff;
        #pragma unroll 1
        for (int t = 0; t < 48; ++t) {
            float v  = pvr[t];
            int   ix = pir[t];
            bool elig   = (v < lastV) || (v == lastV && ix > lastI);
            bool better = (v > bv)    || (v == bv    && ix < bi);
            if (elig && better) { bv = v; bi = ix; }
        }
        tv[j] = bv; ti[j] = bi; lastV = bv; lastI = bi;
    }

    // topk_prob = softmax(tv)   (tv[0] is the max: sorted descending)
    float p[TK]; float Z = 0.f;
    #pragma unroll
    for (int j = 0; j < TK; ++j) { p[j] = expf(tv[j] - tv[0]); Z += p[j]; }
    const float invZ = 1.f / Z;
    #pragma unroll
    for (int j = 0; j < TK; ++j) p[j] *= invZ;

    float4 eh = *(const float4*)(e_h + (size_t)row * 256 + lane * 4);

    float4 nb[TK]; float kw[TK];
    #pragma unroll
    for (int k = 0; k < TK; ++k) {
        float4 n = *(const float4*)(e_t + (size_t)ti[k] * 256 + lane * 4);
        nb[k] = n;
        const float pk = p[k], qk = 1.f - p[k];
        float4 g;
        g.x = tanhf(eh.x + (pk * n.x + qk * eh.x));
        g.y = tanhf(eh.y + (pk * n.y + qk * eh.y));
        g.z = tanhf(eh.z + (pk * n.z + qk * eh.z));
        g.w = tanhf(eh.w + (pk * n.w + qk * eh.w));
        float d = n.x*g.x + n.y*g.y + n.z*g.z + n.w*g.w;
        #pragma unroll
        for (int off = 32; off; off >>= 1) d += __shfl_xor(d, off);
        kw[k] = d;
    }

    // ka_prob = softmax(kw)
    float km = kw[0];
    #pragma unroll
    for (int k = 1; k < TK; ++k) km = fmaxf(km, kw[k]);
    float kz = 0.f; float kp[TK];
    #pragma unroll
    for (int k = 0; k < TK; ++k) { kp[k] = expf(kw[k] - km); kz += kp[k]; }
    const float invKZ = 1.f / kz;

    float4 acc = make_float4(0.f, 0.f, 0.f, 0.f);
    #pragma unroll
    for (int k = 0; k < TK; ++k) {
        acc.x += kp[k] * nb[k].x;
        acc.y += kp[k] * nb[k].y;
        acc.z += kp[k] * nb[k].z;
        acc.w += kp[k] * nb[k].w;
    }
    acc.x *= invKZ; acc.y *= invKZ; acc.z *= invKZ; acc.w *= invKZ;
    *(float4*)(e_Nh + (size_t)row * 256 + lane * 4) = acc;
}

// ---------------------------------------------------------------------------
extern "C" void kernel_launch(void* const* d_in, const int* in_sizes, int n_in,
                              void* d_out, int out_size, void* d_ws, size_t ws_size,
                              hipStream_t stream)
{
    (void)in_sizes; (void)n_in; (void)out_size; (void)ws_size;
    const float* x     = (const float*)d_in[0];
    const float* wsi_w = (const float*)d_in[1];
    const float* wsi_b = (const float*)d_in[2];
    const float* wh_w  = (const float*)d_in[3];
    const float* wh_b  = (const float*)d_in[4];
    const float* wt_w  = (const float*)d_in[5];
    const float* wt_b  = (const float*)d_in[6];
    const float* w1_w  = (const float*)d_in[7];
    const float* w1_b  = (const float*)d_in[8];
    const float* w2_w  = (const float*)d_in[9];
    const float* w2_b  = (const float*)d_in[10];
    float* out = (float*)d_out;
    float* ws  = (float*)d_ws;

    const int M = 12288, Din = 1024, D = 256;
    const size_t ND = (size_t)M * D;          // 3,145,728

    float* h    = ws;                         // reused as e_Nh after K2
    float* e_h  = ws + ND;
    float* e_t  = ws + 2 * ND;
    float* pv   = ws + 3 * ND;                // 12288*4*12 floats
    int*   pi   = (int*)(ws + 3 * ND + (size_t)M * 4 * TK);
    float* e_Nh = h;

    // K1: h = relu(x @ wsi_w + wsi_b)
    gemm_bias<true, 0, false><<<dim3(D/64, M/64), 256, 0, stream>>>(
        x, nullptr, wsi_w, wsi_b, h, M, D, Din);
    // K2: e_h = h @ wh_w + wh_b ; e_t = h @ wt_w + wt_b
    gemm_bias<false, 0, false><<<dim3(D/64, M/64), 256, 0, stream>>>(
        h, nullptr, wh_w, wh_b, e_h, M, D, D);
    gemm_bias<false, 0, false><<<dim3(D/64, M/64), 256, 0, stream>>>(
        h, nullptr, wt_w, wt_b, e_t, M, D, D);
    // K3: fused similarity + partial top-k
    score_topk<<<dim3(4, M/64), 256, 0, stream>>>(e_h, e_t, pv, pi);
    // K4: merge partials + per-row attention tail -> e_Nh (reuses h buffer)
    tail_kernel<<<dim3(M/4), 256, 0, stream>>>(e_h, e_t, pv, pi, e_Nh);
    // K5: out = relu((e_h+e_Nh)@w1+b1) + relu((e_h*e_Nh)@w2+b2)
    gemm_bias<true, 1, false><<<dim3(D/64, M/64), 256, 0, stream>>>(
        e_h, e_Nh, w1_w, w1_b, out, M, D, D);
    gemm_bias<true, 2, true><<<dim3(D/64, M/64), 256, 0, stream>>>(
        e_h, e_Nh, w2_w, w2_b, out, M, D, D);
}

// Round 2
// 4247.564 us; speedup vs baseline: 1.2418x; 1.2418x over previous
//
#include <hip/hip_runtime.h>
#include <hip/hip_bf16.h>
#include <cmath>

#define TK 12

typedef _Float16 f16x8 __attribute__((ext_vector_type(8)));
typedef float    f32x4 __attribute__((ext_vector_type(4)));

// ---------------------------------------------------------------------------
// Generic f32 tiled GEMM: C = [relu]( Aeff @ W + bias )  [+= if ACC]
//   AMODE 0: Aeff = A1;  1: Aeff = A1 + A2;  2: Aeff = A1 * A2
// ---------------------------------------------------------------------------
template<bool RELU, int AMODE, bool ACC>
__global__ __launch_bounds__(256) void gemm_bias(
    const float* __restrict__ A1, const float* __restrict__ A2,
    const float* __restrict__ W, const float* __restrict__ bias,
    float* __restrict__ C, int M, int N, int K)
{
    __shared__ float As[16][68];
    __shared__ float Ws[16][68];
    const int tid = threadIdx.x;
    const int bx = blockIdx.x, by = blockIdx.y;
    const int tx = tid & 15, ty = tid >> 4;
    const int ar = tid >> 2, akq = tid & 3;
    const int wr = tid >> 4, wcq = tid & 15;

    const float* a1p = A1 + (size_t)(by*64 + ar)*K + akq*4;
    const float* a2p = (AMODE != 0) ? (A2 + (size_t)(by*64 + ar)*K + akq*4) : nullptr;
    const float* wp  = W  + (size_t)wr*N + bx*64 + wcq*4;

    float acc[4][4];
    #pragma unroll
    for (int i = 0; i < 4; ++i)
        #pragma unroll
        for (int j = 0; j < 4; ++j) acc[i][j] = 0.f;

    for (int kt = 0; kt < K; kt += 16) {
        float4 a = *(const float4*)(a1p + kt);
        if (AMODE == 1) {
            float4 b = *(const float4*)(a2p + kt);
            a.x += b.x; a.y += b.y; a.z += b.z; a.w += b.w;
        } else if (AMODE == 2) {
            float4 b = *(const float4*)(a2p + kt);
            a.x *= b.x; a.y *= b.y; a.z *= b.z; a.w *= b.w;
        }
        float4 w = *(const float4*)(wp + (size_t)kt * N);
        __syncthreads();
        As[akq*4+0][ar] = a.x;
        As[akq*4+1][ar] = a.y;
        As[akq*4+2][ar] = a.z;
        As[akq*4+3][ar] = a.w;
        *(float4*)&Ws[wr][wcq*4] = w;
        __syncthreads();
        #pragma unroll
        for (int kk = 0; kk < 16; ++kk) {
            float4 av = *(const float4*)&As[kk][ty*4];
            float4 bv = *(const float4*)&Ws[kk][tx*4];
            acc[0][0] += av.x*bv.x; acc[0][1] += av.x*bv.y; acc[0][2] += av.x*bv.z; acc[0][3] += av.x*bv.w;
            acc[1][0] += av.y*bv.x; acc[1][1] += av.y*bv.y; acc[1][2] += av.y*bv.z; acc[1][3] += av.y*bv.w;
            acc[2][0] += av.z*bv.x; acc[2][1] += av.z*bv.y; acc[2][2] += av.z*bv.z; acc[2][3] += av.z*bv.w;
            acc[3][0] += av.w*bv.x; acc[3][1] += av.w*bv.y; acc[3][2] += av.w*bv.z; acc[3][3] += av.w*bv.w;
        }
    }
    const int row0 = by*64 + ty*4, col0 = bx*64 + tx*4;
    const float b0 = bias[col0+0], b1 = bias[col0+1], b2 = bias[col0+2], b3 = bias[col0+3];
    #pragma unroll
    for (int ii = 0; ii < 4; ++ii) {
        float* cp = C + (size_t)(row0+ii)*N + col0;
        float v0 = acc[ii][0] + b0;
        float v1 = acc[ii][1] + b1;
        float v2 = acc[ii][2] + b2;
        float v3 = acc[ii][3] + b3;
        if (RELU) {
            v0 = fmaxf(v0, 0.f); v1 = fmaxf(v1, 0.f);
            v2 = fmaxf(v2, 0.f); v3 = fmaxf(v3, 0.f);
        }
        if (ACC) {
            cp[0] += v0; cp[1] += v1; cp[2] += v2; cp[3] += v3;
        } else {
            cp[0] = v0; cp[1] = v1; cp[2] = v2; cp[3] = v3;
        }
    }
}

// ---------------------------------------------------------------------------
// Split-pack: X (f32 [12288][256], optionally scaled) -> hi/lo f16 in MFMA
// fragment order: P[g][s][l][j] = X[g*16 + (l&15)][s*32 + 8*(l>>4) + j]
// One thread per (g,s,l): writes 16B hi + 16B lo, consecutive (off = tid*8).
// ---------------------------------------------------------------------------
__global__ __launch_bounds__(256) void pack_split(
    const float* __restrict__ X, _Float16* __restrict__ hi,
    _Float16* __restrict__ lo, float scale)
{
    const int tid = blockIdx.x * 256 + threadIdx.x;   // 0..393215
    const int g   = tid >> 9;
    const int rem = tid & 511;
    const int s   = rem >> 6, l = rem & 63;
    const float* src = X + (size_t)(g*16 + (l & 15))*256 + s*32 + 8*(l >> 4);
    float4 v0 = *(const float4*)src;
    float4 v1 = *(const float4*)(src + 4);
    float vv[8] = {v0.x, v0.y, v0.z, v0.w, v1.x, v1.y, v1.z, v1.w};
    f16x8 H, L;
    #pragma unroll
    for (int j = 0; j < 8; ++j) {
        float f = vv[j] * scale;
        _Float16 h = (_Float16)f;
        H[j] = h;
        L[j] = (_Float16)(f - (float)h);
    }
    size_t off = (size_t)tid * 8;
    *(f16x8*)(hi + off) = H;
    *(f16x8*)(lo + off) = L;
}

// branchless exact sorted-desc top-12 insert (med3 trick)
__device__ __forceinline__ void topk_insert(float v, int vi, float tv[TK], int ti[TK])
{
    bool c[TK];
    #pragma unroll
    for (int j = 0; j < TK; ++j) c[j] = v > tv[j];
    #pragma unroll
    for (int j = TK-1; j >= 1; --j) {
        ti[j] = c[j] ? (c[j-1] ? ti[j-1] : vi) : ti[j];
        tv[j] = __builtin_amdgcn_fmed3f(v, tv[j], tv[j-1]);
    }
    ti[0] = c[0] ? vi : ti[0];
    tv[0] = fmaxf(v, tv[0]);
}

// ---------------------------------------------------------------------------
// MFMA score + top-k. Grid (8 col-chunks, 192 row-blocks), 256 threads.
// Block: 64 rows (wave w -> rowgrp blockIdx.y*4+w) x 1536-col chunk.
// 3-term f16-split mfma_f32_16x16x32_f16, swapped (A=et, B=eh) so each
// lane's 4 acc values belong to one e_h row. A-tiles LDS double-buffered,
// shared by all 4 waves. Per-lane sorted top-12 -> per-wave 4-list merge ->
// pv/pi[row][8][12] sorted desc.
// ---------------------------------------------------------------------------
__global__ __launch_bounds__(256) void score_topk_mfma(
    const _Float16* __restrict__ ehh, const _Float16* __restrict__ ehl,
    const _Float16* __restrict__ eth, const _Float16* __restrict__ etl,
    float* __restrict__ pv, int* __restrict__ pi)
{
    __shared__ _Float16 abuf[2][8192];   // 2 x 16KB A-tile (16 cols x 256k x {hi,lo})
    const int tid  = threadIdx.x;
    const int lane = tid & 63;
    const int wave = tid >> 6;
    const int chunk = blockIdx.x;        // 0..7 (1536 cols each)
    const int g = blockIdx.y * 4 + wave; // rowgrp 0..767
    const int cg0 = chunk * 96;          // first colgrp of chunk (96 tiles)

    // B-frags (eh) for this wave's rowgrp: 8 ksteps x {hi,lo}, held in regs
    f16x8 bh[8], bl[8];
    {
        const _Float16* p1 = ehh + (size_t)g*4096 + lane*8;
        const _Float16* p2 = ehl + (size_t)g*4096 + lane*8;
        #pragma unroll
        for (int s = 0; s < 8; ++s) {
            bh[s] = *(const f16x8*)(p1 + s*512);
            bl[s] = *(const f16x8*)(p2 + s*512);
        }
    }

    float tv[TK]; int ti[TK];
    #pragma unroll
    for (int j = 0; j < TK; ++j) { tv[j] = -3.4e38f; ti[j] = 0x7fffffff; }

    // staging: 16 units of 1KB per tile; wave w loads units w*4..w*4+3
    // unit u: kstep s=u>>1, arr=u&1 (0=hi,1=lo); LDS off u*512 halfs
    f16x8 r[4];
    {
        const int t0 = 0;
        #pragma unroll
        for (int i = 0; i < 4; ++i) {
            int u = wave*4 + i;
            const _Float16* srcb = (u & 1) ? etl : eth;
            r[i] = *(const f16x8*)(srcb + (size_t)(cg0 + t0)*4096 + (u>>1)*512 + lane*8);
        }
        #pragma unroll
        for (int i = 0; i < 4; ++i) {
            int u = wave*4 + i;
            *(f16x8*)&abuf[0][u*512 + lane*8] = r[i];
        }
    }
    __syncthreads();

    for (int t = 0; t < 96; ++t) {
        const int cur = t & 1;
        if (t < 95) {
            #pragma unroll
            for (int i = 0; i < 4; ++i) {
                int u = wave*4 + i;
                const _Float16* srcb = (u & 1) ? etl : eth;
                r[i] = *(const f16x8*)(srcb + (size_t)(cg0 + t + 1)*4096 + (u>>1)*512 + lane*8);
            }
        }
        f32x4 acc0 = {0.f,0.f,0.f,0.f};
        f32x4 acc1 = {0.f,0.f,0.f,0.f};
        #pragma unroll
        for (int s = 0; s < 8; ++s) {
            f16x8 ah = *(const f16x8*)&abuf[cur][(2*s+0)*512 + lane*8];
            f16x8 al = *(const f16x8*)&abuf[cur][(2*s+1)*512 + lane*8];
            if (s & 1) {
                acc1 = __builtin_amdgcn_mfma_f32_16x16x32_f16(ah, bh[s], acc1, 0, 0, 0);
                acc1 = __builtin_amdgcn_mfma_f32_16x16x32_f16(ah, bl[s], acc1, 0, 0, 0);
                acc1 = __builtin_amdgcn_mfma_f32_16x16x32_f16(al, bh[s], acc1, 0, 0, 0);
            } else {
                acc0 = __builtin_amdgcn_mfma_f32_16x16x32_f16(ah, bh[s], acc0, 0, 0, 0);
                acc0 = __builtin_amdgcn_mfma_f32_16x16x32_f16(ah, bl[s], acc0, 0, 0, 0);
                acc0 = __builtin_amdgcn_mfma_f32_16x16x32_f16(al, bh[s], acc0, 0, 0, 0);
            }
        }
        const int cb = chunk*1536 + t*16 + 4*(lane >> 4);
        topk_insert(acc0[0] + acc1[0], cb + 0, tv, ti);
        topk_insert(acc0[1] + acc1[1], cb + 1, tv, ti);
        topk_insert(acc0[2] + acc1[2], cb + 2, tv, ti);
        topk_insert(acc0[3] + acc1[3], cb + 3, tv, ti);
        if (t < 95) {
            __syncthreads();
            #pragma unroll
            for (int i = 0; i < 4; ++i) {
                int u = wave*4 + i;
                *(f16x8*)&abuf[cur ^ 1][u*512 + lane*8] = r[i];
            }
            __syncthreads();
        }
    }

    // per-wave merge of 4 lane-lists per row (reuse abuf; all waves done)
    __syncthreads();
    float* mvb = (float*)abuf;           // [4 waves][768] floats then ints
    float* mv  = mvb + wave * 768;
    int*   mi  = (int*)(mvb + 3072) + wave * 768;
    {
        const int rr = lane & 15, t4 = lane >> 4;
        #pragma unroll
        for (int j = 0; j < TK; ++j) {
            mv[rr*48 + t4*TK + j] = tv[j];
            mi[rr*48 + t4*TK + j] = ti[j];
        }
    }
    if (lane < 16) {
        const int rr = lane;
        int ptr[4];
        #pragma unroll
        for (int t = 0; t < 4; ++t) ptr[t] = 0;
        const int row = blockIdx.y*64 + wave*16 + rr;
        float* opv = pv + ((size_t)row*8 + chunk)*TK;
        int*   opi = pi + ((size_t)row*8 + chunk)*TK;
        #pragma unroll 1
        for (int o = 0; o < TK; ++o) {
            float bv = -3.4e38f; int bt = 0, bp = 0;
            #pragma unroll
            for (int t = 0; t < 4; ++t) {
                float hv = mv[rr*48 + t*TK + ptr[t]];
                if (hv > bv) { bv = hv; bt = t; bp = ptr[t]; }
            }
            opv[o] = bv;
            opi[o] = mi[rr*48 + bt*TK + bp];
            #pragma unroll
            for (int t = 0; t < 4; ++t) ptr[t] += (bt == t) ? 1 : 0;
        }
    }
}

// ---------------------------------------------------------------------------
// Per-row tail: merge 8 sorted chunk-lists -> final top-12, softmax, gather,
// gate/ka attention, e_Nh. One wave per row, 4 rows per block.
// ---------------------------------------------------------------------------
__global__ __launch_bounds__(256) void tail_kernel(
    const float* __restrict__ e_h, const float* __restrict__ e_t,
    const float* __restrict__ pv, const int* __restrict__ pi,
    float* __restrict__ e_Nh)
{
    const int lane = threadIdx.x & 63;
    const int wave = threadIdx.x >> 6;
    const int row  = blockIdx.x * 4 + wave;

    const float* pvr = pv + (size_t)row * 96;
    const int*   pir = pi + (size_t)row * 96;

    // all 64 lanes redundantly run the same 8-pointer merge (uniform loads)
    float tv[TK]; int ti[TK];
    int ptr[8];
    #pragma unroll
    for (int t = 0; t < 8; ++t) ptr[t] = 0;
    #pragma unroll 1
    for (int o = 0; o < TK; ++o) {
        float bv = -3.4e38f; int bt = 0, bp = 0;
        #pragma unroll
        for (int t = 0; t < 8; ++t) {
            float hv = pvr[t*TK + ptr[t]];
            if (hv > bv) { bv = hv; bt = t; bp = ptr[t]; }
        }
        tv[o] = bv; ti[o] = pir[bt*TK + bp];
        #pragma unroll
        for (int t = 0; t < 8; ++t) ptr[t] += (bt == t) ? 1 : 0;
    }

    // topk_prob = softmax(tv)  (tv sorted desc; tv[0] is max)
    float p[TK]; float Z = 0.f;
    #pragma unroll
    for (int j = 0; j < TK; ++j) { p[j] = expf(tv[j] - tv[0]); Z += p[j]; }
    const float invZ = 1.f / Z;
    #pragma unroll
    for (int j = 0; j < TK; ++j) p[j] *= invZ;

    float4 eh = *(const float4*)(e_h + (size_t)row * 256 + lane * 4);

    float4 nb[TK]; float kw[TK];
    #pragma unroll
    for (int k = 0; k < TK; ++k) {
        float4 n = *(const float4*)(e_t + (size_t)ti[k] * 256 + lane * 4);
        nb[k] = n;
        const float pk = p[k], qk = 1.f - p[k];
        float4 gt;
        gt.x = tanhf(eh.x + (pk * n.x + qk * eh.x));
        gt.y = tanhf(eh.y + (pk * n.y + qk * eh.y));
        gt.z = tanhf(eh.z + (pk * n.z + qk * eh.z));
        gt.w = tanhf(eh.w + (pk * n.w + qk * eh.w));
        float d = n.x*gt.x + n.y*gt.y + n.z*gt.z + n.w*gt.w;
        #pragma unroll
        for (int off = 32; off; off >>= 1) d += __shfl_xor(d, off);
        kw[k] = d;
    }

    float km = kw[0];
    #pragma unroll
    for (int k = 1; k < TK; ++k) km = fmaxf(km, kw[k]);
    float kz = 0.f; float kp[TK];
    #pragma unroll
    for (int k = 0; k < TK; ++k) { kp[k] = expf(kw[k] - km); kz += kp[k]; }
    const float invKZ = 1.f / kz;

    float4 acc = make_float4(0.f, 0.f, 0.f, 0.f);
    #pragma unroll
    for (int k = 0; k < TK; ++k) {
        acc.x += kp[k] * nb[k].x;
        acc.y += kp[k] * nb[k].y;
        acc.z += kp[k] * nb[k].z;
        acc.w += kp[k] * nb[k].w;
    }
    acc.x *= invKZ; acc.y *= invKZ; acc.z *= invKZ; acc.w *= invKZ;
    *(float4*)(e_Nh + (size_t)row * 256 + lane * 4) = acc;
}

// ---------------------------------------------------------------------------
extern "C" void kernel_launch(void* const* d_in, const int* in_sizes, int n_in,
                              void* d_out, int out_size, void* d_ws, size_t ws_size,
                              hipStream_t stream)
{
    (void)in_sizes; (void)n_in; (void)out_size; (void)ws_size;
    const float* x     = (const float*)d_in[0];
    const float* wsi_w = (const float*)d_in[1];
    const float* wsi_b = (const float*)d_in[2];
    const float* wh_w  = (const float*)d_in[3];
    const float* wh_b  = (const float*)d_in[4];
    const float* wt_w  = (const float*)d_in[5];
    const float* wt_b  = (const float*)d_in[6];
    const float* w1_w  = (const float*)d_in[7];
    const float* w1_b  = (const float*)d_in[8];
    const float* w2_w  = (const float*)d_in[9];
    const float* w2_b  = (const float*)d_in[10];
    float* out = (float*)d_out;
    float* ws  = (float*)d_ws;

    const int M = 12288, Din = 1024, D = 256;
    const size_t ND = (size_t)M * D;              // 3,145,728

    float* h    = ws;                             // reused as e_Nh
    float* e_h  = ws + ND;
    float* e_t  = ws + 2*ND;
    float* pv   = ws + 3*ND;                      // M*8*12 floats
    int*   pi   = (int*)(ws + 3*ND + (size_t)M*8*TK);
    float* e_Nh = h;
    const size_t PKBASE = 3*ND + 2*(size_t)M*8*TK;    // float offset
    const size_t HSLOT  = ND / 2;                     // f16 array in float slots
    _Float16* ehh = (_Float16*)(ws + PKBASE);
    _Float16* ehl = (_Float16*)(ws + PKBASE + HSLOT);
    _Float16* eth = (_Float16*)(ws + PKBASE + 2*HSLOT);
    _Float16* etl = (_Float16*)(ws + PKBASE + 3*HSLOT);

    // K1: h = relu(x @ wsi_w + wsi_b)
    gemm_bias<true, 0, false><<<dim3(D/64, M/64), 256, 0, stream>>>(
        x, nullptr, wsi_w, wsi_b, h, M, D, Din);
    // K2: e_h, e_t
    gemm_bias<false, 0, false><<<dim3(D/64, M/64), 256, 0, stream>>>(
        h, nullptr, wh_w, wh_b, e_h, M, D, D);
    gemm_bias<false, 0, false><<<dim3(D/64, M/64), 256, 0, stream>>>(
        h, nullptr, wt_w, wt_b, e_t, M, D, D);
    // pack: split e_h*SCALE and e_t into fragment-ordered f16 hi/lo
    pack_split<<<1536, 256, 0, stream>>>(e_h, ehh, ehl, 0.0625f);
    pack_split<<<1536, 256, 0, stream>>>(e_t, eth, etl, 1.0f);
    // K3: MFMA similarity + partial top-k (8 chunks)
    score_topk_mfma<<<dim3(8, M/64), 256, 0, stream>>>(ehh, ehl, eth, etl, pv, pi);
    // K4: merge chunks + attention tail -> e_Nh
    tail_kernel<<<dim3(M/4), 256, 0, stream>>>(e_h, e_t, pv, pi, e_Nh);
    // K5: out = relu((e_h+e_Nh)@w1+b1) + relu((e_h*e_Nh)@w2+b2)
    gemm_bias<true, 1, false><<<dim3(D/64, M/64), 256, 0, stream>>>(
        e_h, e_Nh, w1_w, w1_b, out, M, D, D);
    gemm_bias<true, 2, true><<<dim3(D/64, M/64), 256, 0, stream>>>(
        e_h, e_Nh, w2_w, w2_b, out, M, D, D);
}

// Round 3
// 857.297 us; speedup vs baseline: 6.1528x; 4.9546x over previous
//
#include <hip/hip_runtime.h>
#include <hip/hip_bf16.h>
#include <cmath>

#define TK 12
#define NROW 12288
#define NEG_BIG (-3.0e38f)

typedef _Float16 f16x8 __attribute__((ext_vector_type(8)));
typedef float    f32x4 __attribute__((ext_vector_type(4)));

// ---------------------------------------------------------------------------
// Generic f32 tiled GEMM: C = [relu]( Aeff @ W + bias )  [+= if ACC]
//   AMODE 0: Aeff = A1;  1: Aeff = A1 + A2;  2: Aeff = A1 * A2
// ---------------------------------------------------------------------------
template<bool RELU, int AMODE, bool ACC>
__global__ __launch_bounds__(256) void gemm_bias(
    const float* __restrict__ A1, const float* __restrict__ A2,
    const float* __restrict__ W, const float* __restrict__ bias,
    float* __restrict__ C, int M, int N, int K)
{
    __shared__ float As[16][68];
    __shared__ float Ws[16][68];
    const int tid = threadIdx.x;
    const int bx = blockIdx.x, by = blockIdx.y;
    const int tx = tid & 15, ty = tid >> 4;
    const int ar = tid >> 2, akq = tid & 3;
    const int wr = tid >> 4, wcq = tid & 15;

    const float* a1p = A1 + (size_t)(by*64 + ar)*K + akq*4;
    const float* a2p = (AMODE != 0) ? (A2 + (size_t)(by*64 + ar)*K + akq*4) : nullptr;
    const float* wp  = W  + (size_t)wr*N + bx*64 + wcq*4;

    float acc[4][4];
    #pragma unroll
    for (int i = 0; i < 4; ++i)
        #pragma unroll
        for (int j = 0; j < 4; ++j) acc[i][j] = 0.f;

    for (int kt = 0; kt < K; kt += 16) {
        float4 a = *(const float4*)(a1p + kt);
        if (AMODE == 1) {
            float4 b = *(const float4*)(a2p + kt);
            a.x += b.x; a.y += b.y; a.z += b.z; a.w += b.w;
        } else if (AMODE == 2) {
            float4 b = *(const float4*)(a2p + kt);
            a.x *= b.x; a.y *= b.y; a.z *= b.z; a.w *= b.w;
        }
        float4 w = *(const float4*)(wp + (size_t)kt * N);
        __syncthreads();
        As[akq*4+0][ar] = a.x;
        As[akq*4+1][ar] = a.y;
        As[akq*4+2][ar] = a.z;
        As[akq*4+3][ar] = a.w;
        *(float4*)&Ws[wr][wcq*4] = w;
        __syncthreads();
        #pragma unroll
        for (int kk = 0; kk < 16; ++kk) {
            float4 av = *(const float4*)&As[kk][ty*4];
            float4 bv = *(const float4*)&Ws[kk][tx*4];
            acc[0][0] += av.x*bv.x; acc[0][1] += av.x*bv.y; acc[0][2] += av.x*bv.z; acc[0][3] += av.x*bv.w;
            acc[1][0] += av.y*bv.x; acc[1][1] += av.y*bv.y; acc[1][2] += av.y*bv.z; acc[1][3] += av.y*bv.w;
            acc[2][0] += av.z*bv.x; acc[2][1] += av.z*bv.y; acc[2][2] += av.z*bv.z; acc[2][3] += av.z*bv.w;
            acc[3][0] += av.w*bv.x; acc[3][1] += av.w*bv.y; acc[3][2] += av.w*bv.z; acc[3][3] += av.w*bv.w;
        }
    }
    const int row0 = by*64 + ty*4, col0 = bx*64 + tx*4;
    const float b0 = bias[col0+0], b1 = bias[col0+1], b2 = bias[col0+2], b3 = bias[col0+3];
    #pragma unroll
    for (int ii = 0; ii < 4; ++ii) {
        float* cp = C + (size_t)(row0+ii)*N + col0;
        float v0 = acc[ii][0] + b0;
        float v1 = acc[ii][1] + b1;
        float v2 = acc[ii][2] + b2;
        float v3 = acc[ii][3] + b3;
        if (RELU) {
            v0 = fmaxf(v0, 0.f); v1 = fmaxf(v1, 0.f);
            v2 = fmaxf(v2, 0.f); v3 = fmaxf(v3, 0.f);
        }
        if (ACC) {
            cp[0] += v0; cp[1] += v1; cp[2] += v2; cp[3] += v3;
        } else {
            cp[0] = v0; cp[1] = v1; cp[2] = v2; cp[3] = v3;
        }
    }
}

// ---------------------------------------------------------------------------
// Split-pack: X (f32 [12288][256], optionally scaled) -> hi/lo f16 in MFMA
// fragment order: P[g][s][l][j] = X[g*16 + (l&15)][s*32 + 8*(l>>4) + j]
// ---------------------------------------------------------------------------
__global__ __launch_bounds__(256) void pack_split(
    const float* __restrict__ X, _Float16* __restrict__ hi,
    _Float16* __restrict__ lo, float scale)
{
    const int tid = blockIdx.x * 256 + threadIdx.x;   // 0..393215
    const int g   = tid >> 9;
    const int rem = tid & 511;
    const int s   = rem >> 6, l = rem & 63;
    const float* src = X + (size_t)(g*16 + (l & 15))*256 + s*32 + 8*(l >> 4);
    float4 v0 = *(const float4*)src;
    float4 v1 = *(const float4*)(src + 4);
    float vv[8] = {v0.x, v0.y, v0.z, v0.w, v1.x, v1.y, v1.z, v1.w};
    f16x8 H, L;
    #pragma unroll
    for (int j = 0; j < 8; ++j) {
        float f = vv[j] * scale;
        _Float16 h = (_Float16)f;
        H[j] = h;
        L[j] = (_Float16)(f - (float)h);
    }
    size_t off = (size_t)tid * 8;
    *(f16x8*)(hi + off) = H;
    *(f16x8*)(lo + off) = L;
}

// ---------------------------------------------------------------------------
// S1: barrier-free, LDS-free score pass computing per-(row, 32-col-group)
// maxima (2-term f16-split MFMA; selection-grade only). One wave owns 32 rows
// (eh frags in 128 VGPRs) and streams a 1536-col chunk of et-hi fragments
// directly global->VGPR. Group max via 2 fmax + 2 shfl_xor; stored as
// bf16-rounded-DOWN u16 into gmax16[group][row].
// ---------------------------------------------------------------------------
__global__ __launch_bounds__(256, 2) void s1_gmax(
    const _Float16* __restrict__ ehh, const _Float16* __restrict__ ehl,
    const _Float16* __restrict__ eth, unsigned short* __restrict__ gmax16)
{
    const int tid = threadIdx.x, lane = tid & 63, wave = tid >> 6;
    const int chunk = blockIdx.x & 7;               // XCD-affine: XCD = bx%8
    const int rgb = (blockIdx.x >> 3) * 4 + wave;   // rowgroup-of-32: 0..383

    f16x8 bh[2][8], bl[2][8];
    #pragma unroll
    for (int rs = 0; rs < 2; ++rs) {
        const _Float16* p1 = ehh + (size_t)(rgb*2 + rs)*4096 + lane*8;
        const _Float16* p2 = ehl + (size_t)(rgb*2 + rs)*4096 + lane*8;
        #pragma unroll
        for (int s = 0; s < 8; ++s) {
            bh[rs][s] = *(const f16x8*)(p1 + s*512);
            bl[rs][s] = *(const f16x8*)(p2 + s*512);
        }
    }

    float gm0 = NEG_BIG, gm1 = NEG_BIG;
    for (int t = 0; t < 96; ++t) {
        const int gt = chunk*96 + t;
        const _Float16* ap = eth + (size_t)gt*4096 + lane*8;
        f16x8 ah[8];
        #pragma unroll
        for (int s = 0; s < 8; ++s) ah[s] = *(const f16x8*)(ap + s*512);

        f32x4 aE0={0,0,0,0}, aO0={0,0,0,0}, aE1={0,0,0,0}, aO1={0,0,0,0};
        #pragma unroll
        for (int s = 0; s < 8; ++s) {
            if (s & 1) {
                aO0 = __builtin_amdgcn_mfma_f32_16x16x32_f16(ah[s], bh[0][s], aO0, 0,0,0);
                aO0 = __builtin_amdgcn_mfma_f32_16x16x32_f16(ah[s], bl[0][s], aO0, 0,0,0);
                aO1 = __builtin_amdgcn_mfma_f32_16x16x32_f16(ah[s], bh[1][s], aO1, 0,0,0);
                aO1 = __builtin_amdgcn_mfma_f32_16x16x32_f16(ah[s], bl[1][s], aO1, 0,0,0);
            } else {
                aE0 = __builtin_amdgcn_mfma_f32_16x16x32_f16(ah[s], bh[0][s], aE0, 0,0,0);
                aE0 = __builtin_amdgcn_mfma_f32_16x16x32_f16(ah[s], bl[0][s], aE0, 0,0,0);
                aE1 = __builtin_amdgcn_mfma_f32_16x16x32_f16(ah[s], bh[1][s], aE1, 0,0,0);
                aE1 = __builtin_amdgcn_mfma_f32_16x16x32_f16(ah[s], bl[1][s], aE1, 0,0,0);
            }
        }
        f32x4 a0 = aE0 + aO0;
        f32x4 a1 = aE1 + aO1;
        float m0 = fmaxf(fmaxf(a0[0], a0[1]), fmaxf(a0[2], a0[3]));
        float m1 = fmaxf(fmaxf(a1[0], a1[1]), fmaxf(a1[2], a1[3]));
        m0 = fmaxf(m0, __shfl_xor(m0, 16)); m0 = fmaxf(m0, __shfl_xor(m0, 32));
        m1 = fmaxf(m1, __shfl_xor(m1, 16)); m1 = fmaxf(m1, __shfl_xor(m1, 32));
        if (t & 1) {
            gm0 = fmaxf(gm0, m0); gm1 = fmaxf(gm1, m1);
            if (lane < 32) {
                float g = (lane < 16) ? gm0 : gm1;
                unsigned u = (__float_as_uint(g) >> 16) + (g < 0.f ? 1u : 0u);
                gmax16[(size_t)(gt >> 1)*NROW + rgb*32 + (lane & 31)] = (unsigned short)u;
            }
        } else {
            gm0 = m0; gm1 = m1;
        }
    }
}

// ---------------------------------------------------------------------------
// B1: per-row safe threshold tau = (12th-largest 32-group max) - margin.
// Pigeonhole: 12 groups have max >= tau => s12 >= tau. Margin 0.01 covers the
// 2-term-split + bf16-round-down approximation (~30 sigma).
// ---------------------------------------------------------------------------
__global__ __launch_bounds__(256) void b1_tau(
    const unsigned short* __restrict__ gmax16, float* __restrict__ tau)
{
    const int row = blockIdx.x * 256 + threadIdx.x;
    float tv[TK];
    #pragma unroll
    for (int j = 0; j < TK; ++j) tv[j] = NEG_BIG;
    for (int g = 0; g < 384; ++g) {
        unsigned short u = gmax16[(size_t)g*NROW + row];
        float v = __uint_as_float(((unsigned)u) << 16);
        #pragma unroll
        for (int j = TK-1; j >= 1; --j)
            tv[j] = __builtin_amdgcn_fmed3f(v, tv[j], tv[j-1]);
        tv[0] = fmaxf(v, tv[0]);
    }
    tau[row] = tv[TK-1] - 0.01f;
}

// ---------------------------------------------------------------------------
// S2: recompute scores (3-term split, value-grade) and append all elements
// >= tau[row] to per-row candidate lists via global atomics. Barrier-free,
// LDS-free, same streaming structure as S1.
// ---------------------------------------------------------------------------
__global__ __launch_bounds__(256, 2) void s2_collect(
    const _Float16* __restrict__ ehh, const _Float16* __restrict__ ehl,
    const _Float16* __restrict__ eth, const _Float16* __restrict__ etl,
    const float* __restrict__ tau, unsigned int* __restrict__ cnt,
    float2* __restrict__ cand)
{
    const int tid = threadIdx.x, lane = tid & 63, wave = tid >> 6;
    const int chunk = blockIdx.x & 7;
    const int rgb = (blockIdx.x >> 3) * 4 + wave;

    f16x8 bh[2][8], bl[2][8];
    #pragma unroll
    for (int rs = 0; rs < 2; ++rs) {
        const _Float16* p1 = ehh + (size_t)(rgb*2 + rs)*4096 + lane*8;
        const _Float16* p2 = ehl + (size_t)(rgb*2 + rs)*4096 + lane*8;
        #pragma unroll
        for (int s = 0; s < 8; ++s) {
            bh[rs][s] = *(const f16x8*)(p1 + s*512);
            bl[rs][s] = *(const f16x8*)(p2 + s*512);
        }
    }
    const int r0 = rgb*32 + (lane & 15);
    const float tau0 = tau[r0], tau1 = tau[r0 + 16];

    for (int t = 0; t < 96; ++t) {
        const int gt = chunk*96 + t;
        const _Float16* aph = eth + (size_t)gt*4096 + lane*8;
        const _Float16* apl = etl + (size_t)gt*4096 + lane*8;
        f16x8 ah[8], al[8];
        #pragma unroll
        for (int s = 0; s < 8; ++s) ah[s] = *(const f16x8*)(aph + s*512);
        #pragma unroll
        for (int s = 0; s < 8; ++s) al[s] = *(const f16x8*)(apl + s*512);

        f32x4 aE0={0,0,0,0}, aO0={0,0,0,0}, aE1={0,0,0,0}, aO1={0,0,0,0};
        #pragma unroll
        for (int s = 0; s < 8; ++s) {
            if (s & 1) {
                aO0 = __builtin_amdgcn_mfma_f32_16x16x32_f16(ah[s], bh[0][s], aO0, 0,0,0);
                aO0 = __builtin_amdgcn_mfma_f32_16x16x32_f16(ah[s], bl[0][s], aO0, 0,0,0);
                aO0 = __builtin_amdgcn_mfma_f32_16x16x32_f16(al[s], bh[0][s], aO0, 0,0,0);
                aO1 = __builtin_amdgcn_mfma_f32_16x16x32_f16(ah[s], bh[1][s], aO1, 0,0,0);
                aO1 = __builtin_amdgcn_mfma_f32_16x16x32_f16(ah[s], bl[1][s], aO1, 0,0,0);
                aO1 = __builtin_amdgcn_mfma_f32_16x16x32_f16(al[s], bh[1][s], aO1, 0,0,0);
            } else {
                aE0 = __builtin_amdgcn_mfma_f32_16x16x32_f16(ah[s], bh[0][s], aE0, 0,0,0);
                aE0 = __builtin_amdgcn_mfma_f32_16x16x32_f16(ah[s], bl[0][s], aE0, 0,0,0);
                aE0 = __builtin_amdgcn_mfma_f32_16x16x32_f16(al[s], bh[0][s], aE0, 0,0,0);
                aE1 = __builtin_amdgcn_mfma_f32_16x16x32_f16(ah[s], bh[1][s], aE1, 0,0,0);
                aE1 = __builtin_amdgcn_mfma_f32_16x16x32_f16(ah[s], bl[1][s], aE1, 0,0,0);
                aE1 = __builtin_amdgcn_mfma_f32_16x16x32_f16(al[s], bh[1][s], aE1, 0,0,0);
            }
        }
        f32x4 a0 = aE0 + aO0;
        f32x4 a1 = aE1 + aO1;
        float m0 = fmaxf(fmaxf(a0[0], a0[1]), fmaxf(a0[2], a0[3]));
        float m1 = fmaxf(fmaxf(a1[0], a1[1]), fmaxf(a1[2], a1[3]));
        const bool h0 = m0 >= tau0, h1 = m1 >= tau1;
        if (__any(h0 | h1)) {
            const int cb = chunk*1536 + t*16 + 4*(lane >> 4);
            #pragma unroll
            for (int e = 0; e < 4; ++e) {
                if (a0[e] >= tau0) {
                    unsigned p = atomicAdd(&cnt[r0], 1u);
                    if (p < 64) cand[(size_t)r0*64 + p] = make_float2(a0[e], __int_as_float(cb + e));
                }
                if (a1[e] >= tau1) {
                    unsigned p = atomicAdd(&cnt[r0 + 16], 1u);
                    if (p < 64) cand[(size_t)(r0 + 16)*64 + p] = make_float2(a1[e], __int_as_float(cb + e));
                }
            }
        }
    }
}

// ---------------------------------------------------------------------------
// S3: per-row exact top-12 from candidate list (val desc, col asc = jax
// tie-break), then softmax / gather / tanh-gate / ka-softmax / e_Nh.
// One wave per row, 4 rows per block.
// ---------------------------------------------------------------------------
__global__ __launch_bounds__(256) void s3_tail(
    const float* __restrict__ e_h, const float* __restrict__ e_t,
    const unsigned int* __restrict__ cnt, const float2* __restrict__ cand,
    float* __restrict__ e_Nh)
{
    const int lane = threadIdx.x & 63;
    const int wave = threadIdx.x >> 6;
    const int row  = blockIdx.x * 4 + wave;

    const unsigned cn = min(cnt[row], 64u);
    float v = NEG_BIG; int c = 0x7fffffff;
    if (lane < (int)cn) {
        float2 cd = cand[(size_t)row*64 + lane];
        v = cd.x; c = __float_as_int(cd.y);
    }

    float tv[TK]; int ti[TK];
    #pragma unroll
    for (int o = 0; o < TK; ++o) {
        float bv = v; int bc = c;
        #pragma unroll
        for (int off = 32; off; off >>= 1) {
            float ov = __shfl_xor(bv, off);
            int   oc = __shfl_xor(bc, off);
            bool take = (ov > bv) || (ov == bv && oc < bc);
            bv = take ? ov : bv;
            bc = take ? oc : bc;
        }
        tv[o] = bv; ti[o] = bc;
        if (c == bc) v = NEG_BIG;      // retire winner (cols unique per row)
    }

    // topk_prob = softmax(tv)  (tv sorted desc; tv[0] is max)
    float p[TK]; float Z = 0.f;
    #pragma unroll
    for (int j = 0; j < TK; ++j) { p[j] = expf(tv[j] - tv[0]); Z += p[j]; }
    const float invZ = 1.f / Z;
    #pragma unroll
    for (int j = 0; j < TK; ++j) p[j] *= invZ;

    float4 eh = *(const float4*)(e_h + (size_t)row * 256 + lane * 4);

    float4 nb[TK]; float kw[TK];
    #pragma unroll
    for (int k = 0; k < TK; ++k) {
        float4 n = *(const float4*)(e_t + (size_t)ti[k] * 256 + lane * 4);
        nb[k] = n;
        const float pk = p[k], qk = 1.f - p[k];
        float4 gt;
        gt.x = tanhf(eh.x + (pk * n.x + qk * eh.x));
        gt.y = tanhf(eh.y + (pk * n.y + qk * eh.y));
        gt.z = tanhf(eh.z + (pk * n.z + qk * eh.z));
        gt.w = tanhf(eh.w + (pk * n.w + qk * eh.w));
        float d = n.x*gt.x + n.y*gt.y + n.z*gt.z + n.w*gt.w;
        #pragma unroll
        for (int off = 32; off; off >>= 1) d += __shfl_xor(d, off);
        kw[k] = d;
    }

    float km = kw[0];
    #pragma unroll
    for (int k = 1; k < TK; ++k) km = fmaxf(km, kw[k]);
    float kz = 0.f; float kp[TK];
    #pragma unroll
    for (int k = 0; k < TK; ++k) { kp[k] = expf(kw[k] - km); kz += kp[k]; }
    const float invKZ = 1.f / kz;

    float4 acc = make_float4(0.f, 0.f, 0.f, 0.f);
    #pragma unroll
    for (int k = 0; k < TK; ++k) {
        acc.x += kp[k] * nb[k].x;
        acc.y += kp[k] * nb[k].y;
        acc.z += kp[k] * nb[k].z;
        acc.w += kp[k] * nb[k].w;
    }
    acc.x *= invKZ; acc.y *= invKZ; acc.z *= invKZ; acc.w *= invKZ;
    *(float4*)(e_Nh + (size_t)row * 256 + lane * 4) = acc;
}

// ---------------------------------------------------------------------------
extern "C" void kernel_launch(void* const* d_in, const int* in_sizes, int n_in,
                              void* d_out, int out_size, void* d_ws, size_t ws_size,
                              hipStream_t stream)
{
    (void)in_sizes; (void)n_in; (void)out_size; (void)ws_size;
    const float* x     = (const float*)d_in[0];
    const float* wsi_w = (const float*)d_in[1];
    const float* wsi_b = (const float*)d_in[2];
    const float* wh_w  = (const float*)d_in[3];
    const float* wh_b  = (const float*)d_in[4];
    const float* wt_w  = (const float*)d_in[5];
    const float* wt_b  = (const float*)d_in[6];
    const float* w1_w  = (const float*)d_in[7];
    const float* w1_b  = (const float*)d_in[8];
    const float* w2_w  = (const float*)d_in[9];
    const float* w2_b  = (const float*)d_in[10];
    float* out = (float*)d_out;
    float* ws  = (float*)d_ws;

    const int M = NROW, Din = 1024, D = 256;
    const size_t ND = (size_t)M * D;              // 3,145,728

    float* h    = ws;                             // reused as e_Nh
    float* e_h  = ws + ND;
    float* e_t  = ws + 2*ND;
    _Float16* ehh = (_Float16*)(ws + 3*ND);
    _Float16* ehl = (_Float16*)(ws + 3*ND + ND/2);
    _Float16* eth = (_Float16*)(ws + 4*ND);
    _Float16* etl = (_Float16*)(ws + 4*ND + ND/2);
    const size_t GOFF = 5*ND;                     // gmax16: 384*12288 u16
    unsigned short* gmax16 = (unsigned short*)(ws + GOFF);
    const size_t TOFF = GOFF + (size_t)384*NROW/2;
    float* tau = ws + TOFF;
    unsigned int* cnt = (unsigned int*)(ws + TOFF + NROW);
    float2* cand = (float2*)(ws + TOFF + 2*NROW); // 12288*64*2 floats
    float* e_Nh = h;

    // K1: h = relu(x @ wsi_w + wsi_b)
    gemm_bias<true, 0, false><<<dim3(D/64, M/64), 256, 0, stream>>>(
        x, nullptr, wsi_w, wsi_b, h, M, D, Din);
    // K2: e_h, e_t
    gemm_bias<false, 0, false><<<dim3(D/64, M/64), 256, 0, stream>>>(
        h, nullptr, wh_w, wh_b, e_h, M, D, D);
    gemm_bias<false, 0, false><<<dim3(D/64, M/64), 256, 0, stream>>>(
        h, nullptr, wt_w, wt_b, e_t, M, D, D);
    // pack: split e_h*SCALE and e_t into fragment-ordered f16 hi/lo
    pack_split<<<1536, 256, 0, stream>>>(e_h, ehh, ehl, 0.0625f);
    pack_split<<<1536, 256, 0, stream>>>(e_t, eth, etl, 1.0f);
    // S1: per-(row, 32-col-group) maxima
    s1_gmax<<<768, 256, 0, stream>>>(ehh, ehl, eth, gmax16);
    // B1: per-row safe threshold
    b1_tau<<<M/256, 256, 0, stream>>>(gmax16, tau);
    // zero candidate counters, then S2: collect candidates >= tau
    hipMemsetAsync(cnt, 0, (size_t)M*sizeof(unsigned int), stream);
    s2_collect<<<768, 256, 0, stream>>>(ehh, ehl, eth, etl, tau, cnt, cand);
    // S3: exact top-12 + attention tail -> e_Nh
    s3_tail<<<M/4, 256, 0, stream>>>(e_h, e_t, cnt, cand, e_Nh);
    // K5: out = relu((e_h+e_Nh)@w1+b1) + relu((e_h*e_Nh)@w2+b2)
    gemm_bias<true, 1, false><<<dim3(D/64, M/64), 256, 0, stream>>>(
        e_h, e_Nh, w1_w, w1_b, out, M, D, D);
    gemm_bias<true, 2, true><<<dim3(D/64, M/64), 256, 0, stream>>>(
        e_h, e_Nh, w2_w, w2_b, out, M, D, D);
}

// Round 4
// 637.367 us; speedup vs baseline: 8.2758x; 1.3451x over previous
//
#include <hip/hip_runtime.h>
#include <hip/hip_bf16.h>
#include <cmath>

#define TK 12
#define NROW 12288
#define NEG_BIG (-3.0e38f)
#define MFMA16(a,b,c) __builtin_amdgcn_mfma_f32_16x16x32_f16(a,b,c,0,0,0)

typedef _Float16 f16x8 __attribute__((ext_vector_type(8)));
typedef float    f32x4 __attribute__((ext_vector_type(4)));

typedef __attribute__((address_space(1))) const void gvoid_t;
typedef __attribute__((address_space(3))) void lvoid_t;

__device__ __forceinline__ void gload_lds16(const void* g, void* l) {
    __builtin_amdgcn_global_load_lds((gvoid_t*)g, (lvoid_t*)l, 16, 0, 0);
}

// ---------------------------------------------------------------------------
// Generic f32 tiled GEMM: C = [relu]( Aeff @ W + bias )  [+= if ACC]
//   AMODE 0: Aeff = A1;  1: Aeff = A1 + A2;  2: Aeff = A1 * A2
// ---------------------------------------------------------------------------
template<bool RELU, int AMODE, bool ACC>
__global__ __launch_bounds__(256) void gemm_bias(
    const float* __restrict__ A1, const float* __restrict__ A2,
    const float* __restrict__ W, const float* __restrict__ bias,
    float* __restrict__ C, int M, int N, int K)
{
    __shared__ float As[16][68];
    __shared__ float Ws[16][68];
    const int tid = threadIdx.x;
    const int bx = blockIdx.x, by = blockIdx.y;
    const int tx = tid & 15, ty = tid >> 4;
    const int ar = tid >> 2, akq = tid & 3;
    const int wr = tid >> 4, wcq = tid & 15;

    const float* a1p = A1 + (size_t)(by*64 + ar)*K + akq*4;
    const float* a2p = (AMODE != 0) ? (A2 + (size_t)(by*64 + ar)*K + akq*4) : nullptr;
    const float* wp  = W  + (size_t)wr*N + bx*64 + wcq*4;

    float acc[4][4];
    #pragma unroll
    for (int i = 0; i < 4; ++i)
        #pragma unroll
        for (int j = 0; j < 4; ++j) acc[i][j] = 0.f;

    for (int kt = 0; kt < K; kt += 16) {
        float4 a = *(const float4*)(a1p + kt);
        if (AMODE == 1) {
            float4 b = *(const float4*)(a2p + kt);
            a.x += b.x; a.y += b.y; a.z += b.z; a.w += b.w;
        } else if (AMODE == 2) {
            float4 b = *(const float4*)(a2p + kt);
            a.x *= b.x; a.y *= b.y; a.z *= b.z; a.w *= b.w;
        }
        float4 w = *(const float4*)(wp + (size_t)kt * N);
        __syncthreads();
        As[akq*4+0][ar] = a.x;
        As[akq*4+1][ar] = a.y;
        As[akq*4+2][ar] = a.z;
        As[akq*4+3][ar] = a.w;
        *(float4*)&Ws[wr][wcq*4] = w;
        __syncthreads();
        #pragma unroll
        for (int kk = 0; kk < 16; ++kk) {
            float4 av = *(const float4*)&As[kk][ty*4];
            float4 bv = *(const float4*)&Ws[kk][tx*4];
            acc[0][0] += av.x*bv.x; acc[0][1] += av.x*bv.y; acc[0][2] += av.x*bv.z; acc[0][3] += av.x*bv.w;
            acc[1][0] += av.y*bv.x; acc[1][1] += av.y*bv.y; acc[1][2] += av.y*bv.z; acc[1][3] += av.y*bv.w;
            acc[2][0] += av.z*bv.x; acc[2][1] += av.z*bv.y; acc[2][2] += av.z*bv.z; acc[2][3] += av.z*bv.w;
            acc[3][0] += av.w*bv.x; acc[3][1] += av.w*bv.y; acc[3][2] += av.w*bv.z; acc[3][3] += av.w*bv.w;
        }
    }
    const int row0 = by*64 + ty*4, col0 = bx*64 + tx*4;
    const float b0 = bias[col0+0], b1 = bias[col0+1], b2 = bias[col0+2], b3 = bias[col0+3];
    #pragma unroll
    for (int ii = 0; ii < 4; ++ii) {
        float* cp = C + (size_t)(row0+ii)*N + col0;
        float v0 = acc[ii][0] + b0;
        float v1 = acc[ii][1] + b1;
        float v2 = acc[ii][2] + b2;
        float v3 = acc[ii][3] + b3;
        if (RELU) {
            v0 = fmaxf(v0, 0.f); v1 = fmaxf(v1, 0.f);
            v2 = fmaxf(v2, 0.f); v3 = fmaxf(v3, 0.f);
        }
        if (ACC) {
            cp[0] += v0; cp[1] += v1; cp[2] += v2; cp[3] += v3;
        } else {
            cp[0] = v0; cp[1] = v1; cp[2] = v2; cp[3] = v3;
        }
    }
}

// ---------------------------------------------------------------------------
// Split-pack: X (f32 [12288][256], optionally scaled) -> hi/lo f16 in MFMA
// fragment order: P[g][s][l][j] = X[g*16 + (l&15)][s*32 + 8*(l>>4) + j]
// ---------------------------------------------------------------------------
__global__ __launch_bounds__(256) void pack_split(
    const float* __restrict__ X, _Float16* __restrict__ hi,
    _Float16* __restrict__ lo, float scale)
{
    const int tid = blockIdx.x * 256 + threadIdx.x;   // 0..393215
    const int g   = tid >> 9;
    const int rem = tid & 511;
    const int s   = rem >> 6, l = rem & 63;
    const float* src = X + (size_t)(g*16 + (l & 15))*256 + s*32 + 8*(l >> 4);
    float4 v0 = *(const float4*)src;
    float4 v1 = *(const float4*)(src + 4);
    float vv[8] = {v0.x, v0.y, v0.z, v0.w, v1.x, v1.y, v1.z, v1.w};
    f16x8 H, L;
    #pragma unroll
    for (int j = 0; j < 8; ++j) {
        float f = vv[j] * scale;
        _Float16 h = (_Float16)f;
        H[j] = h;
        L[j] = (_Float16)(f - (float)h);
    }
    size_t off = (size_t)tid * 8;
    *(f16x8*)(hi + off) = H;
    *(f16x8*)(lo + off) = L;
}

// ---------------------------------------------------------------------------
// S1: per-(row, 32-col-group) maxima, 1-term f16 (selection grade).
// Block = 4 waves x 32 rows = 128 rows, streaming one 1536-col chunk.
// et-hi tiles staged via global_load_lds into triple-buffered LDS; counted
// vmcnt + raw barrier (loads stay in flight across barriers). Group maxima
// buffered in LDS, flushed once (no vmcnt pollution in loop).
// ---------------------------------------------------------------------------
__global__ __launch_bounds__(256, 3) void s1_gmax(
    const _Float16* __restrict__ ehh, const _Float16* __restrict__ eth,
    unsigned short* __restrict__ gmax16)
{
    __shared__ _Float16 abuf[3][4096];       // 3 x 8KB tile buffers
    __shared__ unsigned short gml[48 * 128]; // [group48][row128]
    const int tid = threadIdx.x, lane = tid & 63, wave = tid >> 6;
    const int chunk = blockIdx.x & 7;
    const int rgb = (blockIdx.x >> 3) * 4 + wave;   // rowgroup-of-32

    f16x8 bh[2][8];
    #pragma unroll
    for (int rs = 0; rs < 2; ++rs) {
        const _Float16* p1 = ehh + (size_t)(rgb*2 + rs)*4096 + lane*8;
        #pragma unroll
        for (int s = 0; s < 8; ++s) bh[rs][s] = *(const f16x8*)(p1 + s*512);
    }
    const _Float16* gsrc = eth + (size_t)chunk*96*4096;
    float gm0 = NEG_BIG, gm1 = NEG_BIG;

    // prologue: stage tiles 0 and 1
    #pragma unroll
    for (int i = 0; i < 2; ++i)
        gload_lds16(gsrc + (wave*2+i)*512 + lane*8, &abuf[0][(wave*2+i)*512]);
    #pragma unroll
    for (int i = 0; i < 2; ++i)
        gload_lds16(gsrc + (size_t)4096 + (wave*2+i)*512 + lane*8, &abuf[1][(wave*2+i)*512]);
    asm volatile("s_waitcnt vmcnt(2) lgkmcnt(0)" ::: "memory");
    __builtin_amdgcn_s_barrier();
    asm volatile("" ::: "memory");

    int cur = 0;
    for (int t = 0; t < 96; ++t) {
        int nx2 = cur - 1; if (nx2 < 0) nx2 = 2;
        if (t + 2 < 96) {
            #pragma unroll
            for (int i = 0; i < 2; ++i)
                gload_lds16(gsrc + (size_t)(t+2)*4096 + (wave*2+i)*512 + lane*8,
                            &abuf[nx2][(wave*2+i)*512]);
        }
        f32x4 aA={0,0,0,0}, aB={0,0,0,0}, aC={0,0,0,0}, aD={0,0,0,0};
        #pragma unroll
        for (int s = 0; s < 8; ++s) {
            f16x8 ah = *(const f16x8*)&abuf[cur][s*512 + lane*8];
            if (s & 1) { aB = MFMA16(ah, bh[0][s], aB); aD = MFMA16(ah, bh[1][s], aD); }
            else       { aA = MFMA16(ah, bh[0][s], aA); aC = MFMA16(ah, bh[1][s], aC); }
        }
        f32x4 a0 = aA + aB, a1 = aC + aD;
        float m0 = fmaxf(fmaxf(a0[0],a0[1]), fmaxf(a0[2],a0[3]));
        float m1 = fmaxf(fmaxf(a1[0],a1[1]), fmaxf(a1[2],a1[3]));
        m0 = fmaxf(m0, __shfl_xor(m0,16)); m0 = fmaxf(m0, __shfl_xor(m0,32));
        m1 = fmaxf(m1, __shfl_xor(m1,16)); m1 = fmaxf(m1, __shfl_xor(m1,32));
        if (t & 1) {
            gm0 = fmaxf(gm0, m0); gm1 = fmaxf(gm1, m1);
            if (lane < 32) {
                float g = (lane < 16) ? gm0 : gm1;
                unsigned u = (__float_as_uint(g) >> 16) + (g < 0.f ? 1u : 0u);
                gml[(t >> 1)*128 + wave*32 + (lane & 31)] = (unsigned short)u;
            }
        } else { gm0 = m0; gm1 = m1; }

        if (t + 2 < 96) { asm volatile("s_waitcnt vmcnt(2)" ::: "memory"); }
        else            { asm volatile("s_waitcnt vmcnt(0)" ::: "memory"); }
        __builtin_amdgcn_s_barrier();
        asm volatile("" ::: "memory");
        cur = (cur >= 2) ? 0 : cur + 1;
    }

    asm volatile("s_waitcnt lgkmcnt(0)" ::: "memory");
    __builtin_amdgcn_s_barrier();
    asm volatile("" ::: "memory");
    const int row0 = (blockIdx.x >> 3) * 128;
    for (int i = tid; i < 48*128; i += 256) {
        const int g = i >> 7, r = i & 127;
        gmax16[(size_t)(chunk*48 + g)*NROW + row0 + r] = gml[i];
    }
}

// ---------------------------------------------------------------------------
// B1: per-row safe threshold tau = (12th-largest 32-group max) - margin.
// ---------------------------------------------------------------------------
__global__ __launch_bounds__(256) void b1_tau(
    const unsigned short* __restrict__ gmax16, float* __restrict__ tau)
{
    const int row = blockIdx.x * 256 + threadIdx.x;
    float tv[TK];
    #pragma unroll
    for (int j = 0; j < TK; ++j) tv[j] = NEG_BIG;
    for (int g = 0; g < 384; ++g) {
        unsigned short u = gmax16[(size_t)g*NROW + row];
        float v = __uint_as_float(((unsigned)u) << 16);
        #pragma unroll
        for (int j = TK-1; j >= 1; --j)
            tv[j] = __builtin_amdgcn_fmed3f(v, tv[j], tv[j-1]);
        tv[0] = fmaxf(v, tv[0]);
    }
    tau[row] = tv[TK-1] - 0.02f;
}

// ---------------------------------------------------------------------------
// S2: 3-term f16 scores (value grade); append elements >= tau[row] to an LDS
// candidate buffer (ds-atomic; no vmcnt pollution), flush once at the end.
// Same triple-buffered LDS staging as S1, 16 units (hi+lo) per tile.
// ---------------------------------------------------------------------------
#define S2CAP 1024
__global__ __launch_bounds__(256, 2) void s2_collect(
    const _Float16* __restrict__ ehh, const _Float16* __restrict__ ehl,
    const _Float16* __restrict__ eth, const _Float16* __restrict__ etl,
    const float* __restrict__ tau, unsigned int* __restrict__ cnt,
    float2* __restrict__ cand)
{
    __shared__ _Float16 abuf[3][8192];       // 3 x 16KB tile buffers
    __shared__ float cval[S2CAP];
    __shared__ int   cmeta[S2CAP];
    __shared__ unsigned int lcnt;
    const int tid = threadIdx.x, lane = tid & 63, wave = tid >> 6;
    const int chunk = blockIdx.x & 7;
    const int rgb = (blockIdx.x >> 3) * 4 + wave;
    if (tid == 0) lcnt = 0;

    f16x8 bh[2][8], bl[2][8];
    #pragma unroll
    for (int rs = 0; rs < 2; ++rs) {
        const _Float16* p1 = ehh + (size_t)(rgb*2 + rs)*4096 + lane*8;
        const _Float16* p2 = ehl + (size_t)(rgb*2 + rs)*4096 + lane*8;
        #pragma unroll
        for (int s = 0; s < 8; ++s) {
            bh[rs][s] = *(const f16x8*)(p1 + s*512);
            bl[rs][s] = *(const f16x8*)(p2 + s*512);
        }
    }
    const int r0 = rgb*32 + (lane & 15);
    const float tau0 = tau[r0], tau1 = tau[r0 + 16];
    const int rl0 = wave*32 + (lane & 15);

    const _Float16* gh = eth + (size_t)chunk*96*4096;
    const _Float16* gl = etl + (size_t)chunk*96*4096;

    // prologue: stage tiles 0,1 (wave stages units 4w..4w+3; unit u: k=u>>1, half=u&1)
    #pragma unroll
    for (int i = 0; i < 4; ++i) {
        const int u = wave*4 + i;
        const _Float16* src = (u & 1) ? gl : gh;
        gload_lds16(src + (u>>1)*512 + lane*8, &abuf[0][u*512]);
    }
    #pragma unroll
    for (int i = 0; i < 4; ++i) {
        const int u = wave*4 + i;
        const _Float16* src = (u & 1) ? gl : gh;
        gload_lds16(src + (size_t)4096 + (u>>1)*512 + lane*8, &abuf[1][u*512]);
    }
    asm volatile("s_waitcnt vmcnt(4) lgkmcnt(0)" ::: "memory");
    __builtin_amdgcn_s_barrier();
    asm volatile("" ::: "memory");

    int cur = 0;
    for (int t = 0; t < 96; ++t) {
        int nx2 = cur - 1; if (nx2 < 0) nx2 = 2;
        if (t + 2 < 96) {
            #pragma unroll
            for (int i = 0; i < 4; ++i) {
                const int u = wave*4 + i;
                const _Float16* src = (u & 1) ? gl : gh;
                gload_lds16(src + (size_t)(t+2)*4096 + (u>>1)*512 + lane*8,
                            &abuf[nx2][u*512]);
            }
        }
        f32x4 c0a={0,0,0,0}, c0b={0,0,0,0}, c0c={0,0,0,0};
        f32x4 c1a={0,0,0,0}, c1b={0,0,0,0}, c1c={0,0,0,0};
        #pragma unroll
        for (int s = 0; s < 8; ++s) {
            f16x8 ah = *(const f16x8*)&abuf[cur][(2*s)*512 + lane*8];
            f16x8 al = *(const f16x8*)&abuf[cur][(2*s+1)*512 + lane*8];
            c0a = MFMA16(ah, bh[0][s], c0a);
            c0b = MFMA16(ah, bl[0][s], c0b);
            c0c = MFMA16(al, bh[0][s], c0c);
            c1a = MFMA16(ah, bh[1][s], c1a);
            c1b = MFMA16(ah, bl[1][s], c1b);
            c1c = MFMA16(al, bh[1][s], c1c);
        }
        f32x4 a0 = c0a + c0b + c0c;
        f32x4 a1 = c1a + c1b + c1c;
        float m0 = fmaxf(fmaxf(a0[0],a0[1]), fmaxf(a0[2],a0[3]));
        float m1 = fmaxf(fmaxf(a1[0],a1[1]), fmaxf(a1[2],a1[3]));
        if (__any(m0 >= tau0 || m1 >= tau1)) {
            const int cb = (chunk*96 + t)*16 + 4*(lane >> 4);
            #pragma unroll
            for (int e = 0; e < 4; ++e) {
                if (a0[e] >= tau0) {
                    unsigned p = atomicAdd(&lcnt, 1u);
                    if (p < S2CAP) { cval[p] = a0[e]; cmeta[p] = (cb + e) | (rl0 << 16); }
                }
                if (a1[e] >= tau1) {
                    unsigned p = atomicAdd(&lcnt, 1u);
                    if (p < S2CAP) { cval[p] = a1[e]; cmeta[p] = (cb + e) | ((rl0 + 16) << 16); }
                }
            }
        }
        if (t + 2 < 96) { asm volatile("s_waitcnt vmcnt(4)" ::: "memory"); }
        else            { asm volatile("s_waitcnt vmcnt(0)" ::: "memory"); }
        __builtin_amdgcn_s_barrier();
        asm volatile("" ::: "memory");
        cur = (cur >= 2) ? 0 : cur + 1;
    }

    asm volatile("s_waitcnt lgkmcnt(0)" ::: "memory");
    __builtin_amdgcn_s_barrier();
    asm volatile("" ::: "memory");
    const int row0 = (blockIdx.x >> 3) * 128;
    const unsigned n = (lcnt < (unsigned)S2CAP) ? lcnt : (unsigned)S2CAP;
    for (unsigned i = tid; i < n; i += 256) {
        const float v = cval[i];
        const int m = cmeta[i];
        const int row = row0 + (m >> 16);
        unsigned p = atomicAdd(&cnt[row], 1u);
        if (p < 64) cand[(size_t)row*64 + p] = make_float2(v, __int_as_float(m & 0xffff));
    }
}

// ---------------------------------------------------------------------------
// S3: per-row exact top-12 from candidate list (val desc, col asc), then
// softmax / gather / tanh-gate / ka-softmax / e_Nh. One wave per row.
// ---------------------------------------------------------------------------
__global__ __launch_bounds__(256) void s3_tail(
    const float* __restrict__ e_h, const float* __restrict__ e_t,
    const unsigned int* __restrict__ cnt, const float2* __restrict__ cand,
    float* __restrict__ e_Nh)
{
    const int lane = threadIdx.x & 63;
    const int wave = threadIdx.x >> 6;
    const int row  = blockIdx.x * 4 + wave;

    const unsigned cn = min(cnt[row], 64u);
    float v = NEG_BIG; int c = 0x7fffffff;
    if (lane < (int)cn) {
        float2 cd = cand[(size_t)row*64 + lane];
        v = cd.x; c = __float_as_int(cd.y);
    }

    float tv[TK]; int ti[TK];
    #pragma unroll
    for (int o = 0; o < TK; ++o) {
        float bv = v; int bc = c;
        #pragma unroll
        for (int off = 32; off; off >>= 1) {
            float ov = __shfl_xor(bv, off);
            int   oc = __shfl_xor(bc, off);
            bool take = (ov > bv) || (ov == bv && oc < bc);
            bv = take ? ov : bv;
            bc = take ? oc : bc;
        }
        tv[o] = bv; ti[o] = bc;
        if (c == bc) v = NEG_BIG;
    }

    float p[TK]; float Z = 0.f;
    #pragma unroll
    for (int j = 0; j < TK; ++j) { p[j] = expf(tv[j] - tv[0]); Z += p[j]; }
    const float invZ = 1.f / Z;
    #pragma unroll
    for (int j = 0; j < TK; ++j) p[j] *= invZ;

    float4 eh = *(const float4*)(e_h + (size_t)row * 256 + lane * 4);

    float4 nb[TK]; float kw[TK];
    #pragma unroll
    for (int k = 0; k < TK; ++k) {
        float4 n = *(const float4*)(e_t + (size_t)ti[k] * 256 + lane * 4);
        nb[k] = n;
        const float pk = p[k], qk = 1.f - p[k];
        float4 gt;
        gt.x = tanhf(eh.x + (pk * n.x + qk * eh.x));
        gt.y = tanhf(eh.y + (pk * n.y + qk * eh.y));
        gt.z = tanhf(eh.z + (pk * n.z + qk * eh.z));
        gt.w = tanhf(eh.w + (pk * n.w + qk * eh.w));
        float d = n.x*gt.x + n.y*gt.y + n.z*gt.z + n.w*gt.w;
        #pragma unroll
        for (int off = 32; off; off >>= 1) d += __shfl_xor(d, off);
        kw[k] = d;
    }

    float km = kw[0];
    #pragma unroll
    for (int k = 1; k < TK; ++k) km = fmaxf(km, kw[k]);
    float kz = 0.f; float kp[TK];
    #pragma unroll
    for (int k = 0; k < TK; ++k) { kp[k] = expf(kw[k] - km); kz += kp[k]; }
    const float invKZ = 1.f / kz;

    float4 acc = make_float4(0.f, 0.f, 0.f, 0.f);
    #pragma unroll
    for (int k = 0; k < TK; ++k) {
        acc.x += kp[k] * nb[k].x;
        acc.y += kp[k] * nb[k].y;
        acc.z += kp[k] * nb[k].z;
        acc.w += kp[k] * nb[k].w;
    }
    acc.x *= invKZ; acc.y *= invKZ; acc.z *= invKZ; acc.w *= invKZ;
    *(float4*)(e_Nh + (size_t)row * 256 + lane * 4) = acc;
}

// ---------------------------------------------------------------------------
extern "C" void kernel_launch(void* const* d_in, const int* in_sizes, int n_in,
                              void* d_out, int out_size, void* d_ws, size_t ws_size,
                              hipStream_t stream)
{
    (void)in_sizes; (void)n_in; (void)out_size; (void)ws_size;
    const float* x     = (const float*)d_in[0];
    const float* wsi_w = (const float*)d_in[1];
    const float* wsi_b = (const float*)d_in[2];
    const float* wh_w  = (const float*)d_in[3];
    const float* wh_b  = (const float*)d_in[4];
    const float* wt_w  = (const float*)d_in[5];
    const float* wt_b  = (const float*)d_in[6];
    const float* w1_w  = (const float*)d_in[7];
    const float* w1_b  = (const float*)d_in[8];
    const float* w2_w  = (const float*)d_in[9];
    const float* w2_b  = (const float*)d_in[10];
    float* out = (float*)d_out;
    float* ws  = (float*)d_ws;

    const int M = NROW, Din = 1024, D = 256;
    const size_t ND = (size_t)M * D;              // 3,145,728

    float* h    = ws;                             // reused as e_Nh
    float* e_h  = ws + ND;
    float* e_t  = ws + 2*ND;
    _Float16* ehh = (_Float16*)(ws + 3*ND);
    _Float16* ehl = (_Float16*)(ws + 3*ND + ND/2);
    _Float16* eth = (_Float16*)(ws + 4*ND);
    _Float16* etl = (_Float16*)(ws + 4*ND + ND/2);
    const size_t GOFF = 5*ND;                     // gmax16: 384*12288 u16
    unsigned short* gmax16 = (unsigned short*)(ws + GOFF);
    const size_t TOFF = GOFF + (size_t)384*NROW/2;
    float* tau = ws + TOFF;
    unsigned int* cnt = (unsigned int*)(ws + TOFF + NROW);
    float2* cand = (float2*)(ws + TOFF + 2*NROW); // 12288*64*2 floats
    float* e_Nh = h;

    // K1: h = relu(x @ wsi_w + wsi_b)
    gemm_bias<true, 0, false><<<dim3(D/64, M/64), 256, 0, stream>>>(
        x, nullptr, wsi_w, wsi_b, h, M, D, Din);
    // K2: e_h, e_t
    gemm_bias<false, 0, false><<<dim3(D/64, M/64), 256, 0, stream>>>(
        h, nullptr, wh_w, wh_b, e_h, M, D, D);
    gemm_bias<false, 0, false><<<dim3(D/64, M/64), 256, 0, stream>>>(
        h, nullptr, wt_w, wt_b, e_t, M, D, D);
    // pack: split e_h*SCALE and e_t into fragment-ordered f16 hi/lo
    pack_split<<<1536, 256, 0, stream>>>(e_h, ehh, ehl, 0.0625f);
    pack_split<<<1536, 256, 0, stream>>>(e_t, eth, etl, 1.0f);
    // S1: per-(row, 32-col-group) maxima (1-term, LDS-staged, counted vmcnt)
    s1_gmax<<<768, 256, 0, stream>>>(ehh, eth, gmax16);
    // B1: per-row safe threshold
    b1_tau<<<M/256, 256, 0, stream>>>(gmax16, tau);
    // zero candidate counters, then S2: collect candidates >= tau
    hipMemsetAsync(cnt, 0, (size_t)M*sizeof(unsigned int), stream);
    s2_collect<<<768, 256, 0, stream>>>(ehh, ehl, eth, etl, tau, cnt, cand);
    // S3: exact top-12 + attention tail -> e_Nh
    s3_tail<<<M/4, 256, 0, stream>>>(e_h, e_t, cnt, cand, e_Nh);
    // K5: out = relu((e_h+e_Nh)@w1+b1) + relu((e_h*e_Nh)@w2+b2)
    gemm_bias<true, 1, false><<<dim3(D/64, M/64), 256, 0, stream>>>(
        e_h, e_Nh, w1_w, w1_b, out, M, D, D);
    gemm_bias<true, 2, true><<<dim3(D/64, M/64), 256, 0, stream>>>(
        e_h, e_Nh, w2_w, w2_b, out, M, D, D);
}

// Round 5
// 473.851 us; speedup vs baseline: 11.1316x; 1.3451x over previous
//
#include <hip/hip_runtime.h>
#include <hip/hip_bf16.h>
#include <cmath>

#define TK 12
#define NROW 12288
#define NEG_BIG (-3.0e38f)
#define MFMA16(a,b,c) __builtin_amdgcn_mfma_f32_16x16x32_f16(a,b,c,0,0,0)

typedef _Float16 f16x8 __attribute__((ext_vector_type(8)));
typedef float    f32x4 __attribute__((ext_vector_type(4)));

typedef __attribute__((address_space(1))) const void gvoid_t;
typedef __attribute__((address_space(3))) void lvoid_t;
__device__ __forceinline__ void gload_lds16(const void* g, void* l) {
    __builtin_amdgcn_global_load_lds((gvoid_t*)g, (lvoid_t*)l, 16, 0, 0);
}

// ---------------------------------------------------------------------------
// wpack: W [K][N] f32 -> A-operand fragments of W^T, hi/lo f16.
// P[cg][s][l][j] = W[s*32 + 8*(l>>4) + j][cg*16 + (l&15)], linear idx = tid*8.
// ---------------------------------------------------------------------------
__global__ __launch_bounds__(256) void wpack(
    const float* __restrict__ W, _Float16* __restrict__ hi,
    _Float16* __restrict__ lo, int N, int nkt)
{
    const int tid = blockIdx.x * 256 + threadIdx.x;
    const int l = tid & 63;
    const int s = (tid >> 6) % nkt;
    const int cg = tid / (nkt * 64);
    const int krow = s * 32 + 8 * (l >> 4);
    const int col = cg * 16 + (l & 15);
    f16x8 H, L;
    #pragma unroll
    for (int j = 0; j < 8; ++j) {
        float w = W[(size_t)(krow + j) * N + col];
        _Float16 h = (_Float16)w;
        H[j] = h;
        L[j] = (_Float16)(w - (float)h);
    }
    *(f16x8*)(hi + (size_t)tid * 8) = H;
    *(f16x8*)(lo + (size_t)tid * 8) = L;
}

// ---------------------------------------------------------------------------
// gemm_mfma: C[12288][256] = act( Aeff @ W + bias ), 3-term f16-split MFMA.
//   AMODE 0: Aeff=A1; 1: A1+A2; 2: A1*A2.   Grid (2, 192), 256 thr.
// Block = 64 rows x 128 cols (8 colgroups); wave owns 2 colgroups x 64 rows.
// A staged from f32 (convert hi/lo in-flight); W pre-packed (wpack layout).
// ---------------------------------------------------------------------------
template<int AMODE, bool RELU, bool ACC>
__global__ __launch_bounds__(256) void gemm_mfma(
    const float* __restrict__ A1, const float* __restrict__ A2,
    const _Float16* __restrict__ Wh, const _Float16* __restrict__ Wl,
    const float* __restrict__ bias, float* __restrict__ C, int K)
{
    __shared__ _Float16 aH[4*64*8], aL[4*64*8];
    __shared__ _Float16 wH[8*64*8], wL[8*64*8];
    const int tid = threadIdx.x, lane = tid & 63, wave = tid >> 6;
    const int rb = blockIdx.y * 64;
    const int cbg = blockIdx.x * 8;
    const int nkt = K >> 5;

    const int arow = rb + (tid >> 6) * 16 + (lane & 15);
    const int acol0 = 8 * (lane >> 4);
    const float* a1p = A1 + (size_t)arow * K + acol0;
    const float* a2p = (AMODE != 0) ? (A2 + (size_t)arow * K + acol0) : nullptr;

    f32x4 acc[4][2];
    #pragma unroll
    for (int rg = 0; rg < 4; ++rg)
        #pragma unroll
        for (int c = 0; c < 2; ++c) acc[rg][c] = (f32x4){0.f,0.f,0.f,0.f};

    for (int kt = 0; kt < nkt; ++kt) {
        __syncthreads();
        // stage A (convert f32 -> hi/lo f16)
        {
            float v[8];
            *(float4*)v       = *(const float4*)(a1p + kt*32);
            *(float4*)(v + 4) = *(const float4*)(a1p + kt*32 + 4);
            if (AMODE == 1) {
                float4 b0 = *(const float4*)(a2p + kt*32);
                float4 b1 = *(const float4*)(a2p + kt*32 + 4);
                v[0]+=b0.x; v[1]+=b0.y; v[2]+=b0.z; v[3]+=b0.w;
                v[4]+=b1.x; v[5]+=b1.y; v[6]+=b1.z; v[7]+=b1.w;
            } else if (AMODE == 2) {
                float4 b0 = *(const float4*)(a2p + kt*32);
                float4 b1 = *(const float4*)(a2p + kt*32 + 4);
                v[0]*=b0.x; v[1]*=b0.y; v[2]*=b0.z; v[3]*=b0.w;
                v[4]*=b1.x; v[5]*=b1.y; v[6]*=b1.z; v[7]*=b1.w;
            }
            f16x8 H, L;
            #pragma unroll
            for (int j = 0; j < 8; ++j) {
                _Float16 h = (_Float16)v[j];
                H[j] = h;
                L[j] = (_Float16)(v[j] - (float)h);
            }
            *(f16x8*)&aH[tid*8] = H;
            *(f16x8*)&aL[tid*8] = L;
        }
        // stage W (pre-packed frags): 512 slots, 2 per thread
        #pragma unroll
        for (int i = 0; i < 2; ++i) {
            const int slot = tid + i*256;
            const int c = slot >> 6, l2 = slot & 63;
            const size_t goff = ((size_t)(cbg + c) * nkt + kt) * 512 + l2*8;
            *(f16x8*)&wH[slot*8] = *(const f16x8*)(Wh + goff);
            *(f16x8*)&wL[slot*8] = *(const f16x8*)(Wl + goff);
        }
        __syncthreads();
        // compute
        f16x8 wh0 = *(const f16x8*)&wH[((wave*2+0)*64 + lane)*8];
        f16x8 wl0 = *(const f16x8*)&wL[((wave*2+0)*64 + lane)*8];
        f16x8 wh1 = *(const f16x8*)&wH[((wave*2+1)*64 + lane)*8];
        f16x8 wl1 = *(const f16x8*)&wL[((wave*2+1)*64 + lane)*8];
        #pragma unroll
        for (int rg = 0; rg < 4; ++rg) {
            f16x8 ah = *(const f16x8*)&aH[(rg*64 + lane)*8];
            f16x8 al = *(const f16x8*)&aL[(rg*64 + lane)*8];
            acc[rg][0] = MFMA16(wh0, ah, acc[rg][0]);
            acc[rg][0] = MFMA16(wl0, ah, acc[rg][0]);
            acc[rg][0] = MFMA16(wh0, al, acc[rg][0]);
            acc[rg][1] = MFMA16(wh1, ah, acc[rg][1]);
            acc[rg][1] = MFMA16(wl1, ah, acc[rg][1]);
            acc[rg][1] = MFMA16(wh1, al, acc[rg][1]);
        }
    }
    // epilogue
    #pragma unroll
    for (int rg = 0; rg < 4; ++rg) {
        const int row = rb + rg*16 + (lane & 15);
        #pragma unroll
        for (int c = 0; c < 2; ++c) {
            const int col = (cbg + wave*2 + c)*16 + 4*(lane >> 4);
            float4 b4 = *(const float4*)(bias + col);
            float4 o;
            o.x = acc[rg][c][0] + b4.x;
            o.y = acc[rg][c][1] + b4.y;
            o.z = acc[rg][c][2] + b4.z;
            o.w = acc[rg][c][3] + b4.w;
            if (RELU) {
                o.x = fmaxf(o.x, 0.f); o.y = fmaxf(o.y, 0.f);
                o.z = fmaxf(o.z, 0.f); o.w = fmaxf(o.w, 0.f);
            }
            float* cp = C + (size_t)row*256 + col;
            if (ACC) {
                float4 prev = *(const float4*)cp;
                o.x += prev.x; o.y += prev.y; o.z += prev.z; o.w += prev.w;
            }
            *(float4*)cp = o;
        }
    }
}

// ---------------------------------------------------------------------------
// pack_hi: X f32 [12288][256] (scaled) -> hi f16 in MFMA fragment order.
// P[g][s][l][j] = X[g*16 + (l&15)][s*32 + 8*(l>>4) + j]
// ---------------------------------------------------------------------------
__global__ __launch_bounds__(256) void pack_hi(
    const float* __restrict__ X, _Float16* __restrict__ hi, float scale)
{
    const int tid = blockIdx.x * 256 + threadIdx.x;
    const int g = tid >> 9;
    const int rem = tid & 511;
    const int s = rem >> 6, l = rem & 63;
    const float* src = X + (size_t)(g*16 + (l & 15))*256 + s*32 + 8*(l >> 4);
    float4 v0 = *(const float4*)src;
    float4 v1 = *(const float4*)(src + 4);
    float vv[8] = {v0.x, v0.y, v0.z, v0.w, v1.x, v1.y, v1.z, v1.w};
    f16x8 H;
    #pragma unroll
    for (int j = 0; j < 8; ++j) H[j] = (_Float16)(vv[j] * scale);
    *(f16x8*)(hi + (size_t)tid * 8) = H;
}

// ---------------------------------------------------------------------------
// S1: per-(row, 32-col-group) maxima, 1-term f16. Block = 4 waves x 64 rows
// = 256 rows, one 1536-col chunk. Triple-buffered global_load_lds + counted
// vmcnt. Group maxima buffered in LDS (bf16 round-down), flushed once.
// ---------------------------------------------------------------------------
__global__ __launch_bounds__(256) void s1_gmax(
    const _Float16* __restrict__ ehh, const _Float16* __restrict__ eth,
    unsigned short* __restrict__ gmax16)
{
    __shared__ _Float16 abuf[3][4096];          // 3 x 8KB tiles
    __shared__ unsigned short gml[48 * 256];    // 24KB
    const int tid = threadIdx.x, lane = tid & 63, wave = tid >> 6;
    const int chunk = blockIdx.x & 7;
    const int rblk = blockIdx.x >> 3;           // 0..47
    const int rg0 = rblk * 16 + wave * 4;

    f16x8 bh[4][8];
    #pragma unroll
    for (int rg = 0; rg < 4; ++rg) {
        const _Float16* p = ehh + (size_t)(rg0 + rg)*4096 + lane*8;
        #pragma unroll
        for (int s = 0; s < 8; ++s) bh[rg][s] = *(const f16x8*)(p + s*512);
    }
    const _Float16* gsrc = eth + (size_t)chunk * 96 * 4096;

    #pragma unroll
    for (int i = 0; i < 2; ++i)
        gload_lds16(gsrc + (wave*2+i)*512 + lane*8, &abuf[0][(wave*2+i)*512]);
    #pragma unroll
    for (int i = 0; i < 2; ++i)
        gload_lds16(gsrc + 4096 + (wave*2+i)*512 + lane*8, &abuf[1][(wave*2+i)*512]);
    asm volatile("s_waitcnt vmcnt(2) lgkmcnt(0)" ::: "memory");
    __builtin_amdgcn_s_barrier();
    asm volatile("" ::: "memory");

    float gm[4] = {NEG_BIG, NEG_BIG, NEG_BIG, NEG_BIG};
    int cur = 0;
    for (int t = 0; t < 96; ++t) {
        int nx2 = cur - 1; if (nx2 < 0) nx2 = 2;
        if (t + 2 < 96) {
            #pragma unroll
            for (int i = 0; i < 2; ++i)
                gload_lds16(gsrc + (size_t)(t+2)*4096 + (wave*2+i)*512 + lane*8,
                            &abuf[nx2][(wave*2+i)*512]);
        }
        f32x4 aE[4], aO[4];
        #pragma unroll
        for (int rg = 0; rg < 4; ++rg) {
            aE[rg] = (f32x4){0.f,0.f,0.f,0.f};
            aO[rg] = (f32x4){0.f,0.f,0.f,0.f};
        }
        #pragma unroll
        for (int s = 0; s < 8; ++s) {
            f16x8 ah = *(const f16x8*)&abuf[cur][s*512 + lane*8];
            if (s & 1) {
                #pragma unroll
                for (int rg = 0; rg < 4; ++rg) aO[rg] = MFMA16(ah, bh[rg][s], aO[rg]);
            } else {
                #pragma unroll
                for (int rg = 0; rg < 4; ++rg) aE[rg] = MFMA16(ah, bh[rg][s], aE[rg]);
            }
        }
        #pragma unroll
        for (int rg = 0; rg < 4; ++rg) {
            f32x4 a = aE[rg] + aO[rg];
            float m = fmaxf(fmaxf(a[0],a[1]), fmaxf(a[2],a[3]));
            m = fmaxf(m, __shfl_xor(m, 16));
            m = fmaxf(m, __shfl_xor(m, 32));
            gm[rg] = (t & 1) ? fmaxf(gm[rg], m) : m;
        }
        if ((t & 1) && lane < 16) {
            #pragma unroll
            for (int rg = 0; rg < 4; ++rg) {
                float g = gm[rg];
                unsigned u = (__float_as_uint(g) >> 16) + (g < 0.f ? 1u : 0u);
                gml[(t>>1)*256 + wave*64 + rg*16 + lane] = (unsigned short)u;
            }
        }
        if (t + 2 < 96) { asm volatile("s_waitcnt vmcnt(2)" ::: "memory"); }
        else            { asm volatile("s_waitcnt vmcnt(0)" ::: "memory"); }
        __builtin_amdgcn_s_barrier();
        asm volatile("" ::: "memory");
        cur = (cur >= 2) ? 0 : cur + 1;
    }
    asm volatile("s_waitcnt lgkmcnt(0)" ::: "memory");
    __builtin_amdgcn_s_barrier();
    asm volatile("" ::: "memory");
    const int row0 = rblk * 256;
    for (int i = tid; i < 48*256; i += 256) {
        const int g = i >> 8, r = i & 255;
        gmax16[(size_t)(chunk*48 + g)*NROW + row0 + r] = gml[i];
    }
}

// ---------------------------------------------------------------------------
// B1: tau[row] = (12th-largest 32-col-group max) - margin.
// ---------------------------------------------------------------------------
__global__ __launch_bounds__(256) void b1_tau(
    const unsigned short* __restrict__ gmax16, float* __restrict__ tau)
{
    const int row = blockIdx.x * 256 + threadIdx.x;
    float tv[TK];
    #pragma unroll
    for (int j = 0; j < TK; ++j) tv[j] = NEG_BIG;
    for (int g = 0; g < 384; ++g) {
        unsigned short u = gmax16[(size_t)g*NROW + row];
        float v = __uint_as_float(((unsigned)u) << 16);
        #pragma unroll
        for (int j = TK-1; j >= 1; --j)
            tv[j] = __builtin_amdgcn_fmed3f(v, tv[j], tv[j-1]);
        tv[0] = fmaxf(v, tv[0]);
    }
    tau[row] = tv[TK-1] - 0.02f;
}

// ---------------------------------------------------------------------------
// S2: 1-term scores; collect columns >= tau[row] into LDS, flush once.
// Same structure as S1 (256 rows/block, hi-only tiles).
// ---------------------------------------------------------------------------
#define S2CAP 1536
__global__ __launch_bounds__(256) void s2_collect(
    const _Float16* __restrict__ ehh, const _Float16* __restrict__ eth,
    const float* __restrict__ tau, unsigned int* __restrict__ cnt,
    int* __restrict__ cand)
{
    __shared__ _Float16 abuf[3][4096];
    __shared__ int cmeta[S2CAP];
    __shared__ unsigned int lcnt;
    const int tid = threadIdx.x, lane = tid & 63, wave = tid >> 6;
    const int chunk = blockIdx.x & 7;
    const int rblk = blockIdx.x >> 3;
    const int rg0 = rblk * 16 + wave * 4;
    if (tid == 0) lcnt = 0;

    f16x8 bh[4][8];
    #pragma unroll
    for (int rg = 0; rg < 4; ++rg) {
        const _Float16* p = ehh + (size_t)(rg0 + rg)*4096 + lane*8;
        #pragma unroll
        for (int s = 0; s < 8; ++s) bh[rg][s] = *(const f16x8*)(p + s*512);
    }
    float tv[4];
    #pragma unroll
    for (int rg = 0; rg < 4; ++rg)
        tv[rg] = tau[rblk*256 + wave*64 + rg*16 + (lane & 15)];

    const _Float16* gsrc = eth + (size_t)chunk * 96 * 4096;
    #pragma unroll
    for (int i = 0; i < 2; ++i)
        gload_lds16(gsrc + (wave*2+i)*512 + lane*8, &abuf[0][(wave*2+i)*512]);
    #pragma unroll
    for (int i = 0; i < 2; ++i)
        gload_lds16(gsrc + 4096 + (wave*2+i)*512 + lane*8, &abuf[1][(wave*2+i)*512]);
    asm volatile("s_waitcnt vmcnt(2) lgkmcnt(0)" ::: "memory");
    __builtin_amdgcn_s_barrier();
    asm volatile("" ::: "memory");

    int cur = 0;
    for (int t = 0; t < 96; ++t) {
        int nx2 = cur - 1; if (nx2 < 0) nx2 = 2;
        if (t + 2 < 96) {
            #pragma unroll
            for (int i = 0; i < 2; ++i)
                gload_lds16(gsrc + (size_t)(t+2)*4096 + (wave*2+i)*512 + lane*8,
                            &abuf[nx2][(wave*2+i)*512]);
        }
        f32x4 aE[4], aO[4];
        #pragma unroll
        for (int rg = 0; rg < 4; ++rg) {
            aE[rg] = (f32x4){0.f,0.f,0.f,0.f};
            aO[rg] = (f32x4){0.f,0.f,0.f,0.f};
        }
        #pragma unroll
        for (int s = 0; s < 8; ++s) {
            f16x8 ah = *(const f16x8*)&abuf[cur][s*512 + lane*8];
            if (s & 1) {
                #pragma unroll
                for (int rg = 0; rg < 4; ++rg) aO[rg] = MFMA16(ah, bh[rg][s], aO[rg]);
            } else {
                #pragma unroll
                for (int rg = 0; rg < 4; ++rg) aE[rg] = MFMA16(ah, bh[rg][s], aE[rg]);
            }
        }
        const int cb = (chunk*96 + t)*16 + 4*(lane >> 4);
        #pragma unroll
        for (int rg = 0; rg < 4; ++rg) {
            f32x4 a = aE[rg] + aO[rg];
            float m = fmaxf(fmaxf(a[0],a[1]), fmaxf(a[2],a[3]));
            if (__any(m >= tv[rg])) {
                const int lrow = wave*64 + rg*16 + (lane & 15);
                #pragma unroll
                for (int e = 0; e < 4; ++e) {
                    if (a[e] >= tv[rg]) {
                        unsigned p = atomicAdd(&lcnt, 1u);
                        if (p < S2CAP) cmeta[p] = (cb + e) | (lrow << 16);
                    }
                }
            }
        }
        if (t + 2 < 96) { asm volatile("s_waitcnt vmcnt(2)" ::: "memory"); }
        else            { asm volatile("s_waitcnt vmcnt(0)" ::: "memory"); }
        __builtin_amdgcn_s_barrier();
        asm volatile("" ::: "memory");
        cur = (cur >= 2) ? 0 : cur + 1;
    }
    asm volatile("s_waitcnt lgkmcnt(0)" ::: "memory");
    __builtin_amdgcn_s_barrier();
    asm volatile("" ::: "memory");
    const int row0 = rblk * 256;
    const unsigned n = (lcnt < (unsigned)S2CAP) ? lcnt : (unsigned)S2CAP;
    for (unsigned i = tid; i < n; i += 256) {
        const int m = cmeta[i];
        const int row = row0 + (m >> 16);
        unsigned p = atomicAdd(&cnt[row], 1u);
        if (p < 64) cand[(size_t)row*64 + p] = m & 0xffff;
    }
}

// ---------------------------------------------------------------------------
// S3: exact f32 rescoring of candidates, top-12 (val desc, col asc),
// softmax / gather / tanh-gate / ka-softmax / e_Nh. One wave per row.
// ---------------------------------------------------------------------------
__global__ __launch_bounds__(256) void s3_tail(
    const float* __restrict__ e_h, const float* __restrict__ e_t,
    const unsigned int* __restrict__ cnt, const int* __restrict__ cand,
    float* __restrict__ e_Nh)
{
    const int lane = threadIdx.x & 63;
    const int wave = threadIdx.x >> 6;
    const int row  = blockIdx.x * 4 + wave;

    const unsigned cn = min(cnt[row], 64u);
    const bool act = lane < (int)cn;
    int colc = act ? cand[(size_t)row*64 + lane] : 0x7fffffff;

    const float* ehr = e_h + (size_t)row * 256;
    const float* etr = e_t + (size_t)(act ? colc : 0) * 256;
    float s = 0.f;
    for (int k = 0; k < 64; ++k) {
        float4 a = *(const float4*)(ehr + k*4);
        float4 b = *(const float4*)(etr + k*4);
        s += a.x*b.x + a.y*b.y + a.z*b.z + a.w*b.w;
    }
    s *= 0.0625f;
    if (!act) s = NEG_BIG;

    float tvv[TK]; int ti[TK];
    float v = s; int c = colc;
    #pragma unroll
    for (int o = 0; o < TK; ++o) {
        float bv = v; int bc = c;
        #pragma unroll
        for (int off = 32; off; off >>= 1) {
            float ov = __shfl_xor(bv, off);
            int   oc = __shfl_xor(bc, off);
            bool take = (ov > bv) || (ov == bv && oc < bc);
            bv = take ? ov : bv;
            bc = take ? oc : bc;
        }
        tvv[o] = bv; ti[o] = bc;
        if (c == bc) v = NEG_BIG;
    }

    float p[TK]; float Z = 0.f;
    #pragma unroll
    for (int j = 0; j < TK; ++j) { p[j] = expf(tvv[j] - tvv[0]); Z += p[j]; }
    const float invZ = 1.f / Z;
    #pragma unroll
    for (int j = 0; j < TK; ++j) p[j] *= invZ;

    float4 eh = *(const float4*)(ehr + lane * 4);

    float4 nb[TK]; float kw[TK];
    #pragma unroll
    for (int k = 0; k < TK; ++k) {
        float4 n = *(const float4*)(e_t + (size_t)ti[k] * 256 + lane * 4);
        nb[k] = n;
        const float pk = p[k], qk = 1.f - p[k];
        float4 gt;
        gt.x = tanhf(eh.x + (pk * n.x + qk * eh.x));
        gt.y = tanhf(eh.y + (pk * n.y + qk * eh.y));
        gt.z = tanhf(eh.z + (pk * n.z + qk * eh.z));
        gt.w = tanhf(eh.w + (pk * n.w + qk * eh.w));
        float d = n.x*gt.x + n.y*gt.y + n.z*gt.z + n.w*gt.w;
        #pragma unroll
        for (int off = 32; off; off >>= 1) d += __shfl_xor(d, off);
        kw[k] = d;
    }

    float km = kw[0];
    #pragma unroll
    for (int k = 1; k < TK; ++k) km = fmaxf(km, kw[k]);
    float kz = 0.f; float kp[TK];
    #pragma unroll
    for (int k = 0; k < TK; ++k) { kp[k] = expf(kw[k] - km); kz += kp[k]; }
    const float invKZ = 1.f / kz;

    float4 acc = make_float4(0.f, 0.f, 0.f, 0.f);
    #pragma unroll
    for (int k = 0; k < TK; ++k) {
        acc.x += kp[k] * nb[k].x;
        acc.y += kp[k] * nb[k].y;
        acc.z += kp[k] * nb[k].z;
        acc.w += kp[k] * nb[k].w;
    }
    acc.x *= invKZ; acc.y *= invKZ; acc.z *= invKZ; acc.w *= invKZ;
    *(float4*)(e_Nh + (size_t)row * 256 + lane * 4) = acc;
}

// ---------------------------------------------------------------------------
extern "C" void kernel_launch(void* const* d_in, const int* in_sizes, int n_in,
                              void* d_out, int out_size, void* d_ws, size_t ws_size,
                              hipStream_t stream)
{
    (void)in_sizes; (void)n_in; (void)out_size; (void)ws_size;
    const float* x     = (const float*)d_in[0];
    const float* wsi_w = (const float*)d_in[1];
    const float* wsi_b = (const float*)d_in[2];
    const float* wh_w  = (const float*)d_in[3];
    const float* wh_b  = (const float*)d_in[4];
    const float* wt_w  = (const float*)d_in[5];
    const float* wt_b  = (const float*)d_in[6];
    const float* w1_w  = (const float*)d_in[7];
    const float* w1_b  = (const float*)d_in[8];
    const float* w2_w  = (const float*)d_in[9];
    const float* w2_b  = (const float*)d_in[10];
    float* out = (float*)d_out;
    float* ws  = (float*)d_ws;

    const int M = NROW;
    const size_t ND = (size_t)M * 256;            // 3,145,728

    float* h    = ws;                             // reused as e_Nh
    float* e_h  = ws + ND;
    float* e_t  = ws + 2*ND;
    _Float16* ehh = (_Float16*)(ws + 3*ND);       // ND halfs
    _Float16* eth = (_Float16*)(ws + 3*ND + ND/2);
    size_t o = 4*ND;
    unsigned short* gmax16 = (unsigned short*)(ws + o); o += (size_t)384*NROW/2;
    float* tau = ws + o;                          o += NROW;
    unsigned int* cnt = (unsigned int*)(ws + o);  o += NROW;
    int* cand = (int*)(ws + o);                   o += (size_t)NROW*64;
    _Float16* hp = (_Float16*)(ws + o);
    _Float16* wsiH = hp;                 // 1024*256 halfs
    _Float16* wsiL = hp + 262144;
    _Float16* whH  = hp + 524288;        // 256*256 each below
    _Float16* whL  = hp + 524288 + 65536;
    _Float16* wtH  = hp + 524288 + 2*65536;
    _Float16* wtL  = hp + 524288 + 3*65536;
    _Float16* w1H  = hp + 524288 + 4*65536;
    _Float16* w1L  = hp + 524288 + 5*65536;
    _Float16* w2H  = hp + 524288 + 6*65536;
    _Float16* w2L  = hp + 524288 + 7*65536;
    float* e_Nh = h;

    // pack weights into fragment layout
    wpack<<<128, 256, 0, stream>>>(wsi_w, wsiH, wsiL, 256, 32);
    wpack<<<32, 256, 0, stream>>>(wh_w, whH, whL, 256, 8);
    wpack<<<32, 256, 0, stream>>>(wt_w, wtH, wtL, 256, 8);
    wpack<<<32, 256, 0, stream>>>(w1_w, w1H, w1L, 256, 8);
    wpack<<<32, 256, 0, stream>>>(w2_w, w2H, w2L, 256, 8);

    // K1: h = relu(x @ wsi + b)
    gemm_mfma<0, true, false><<<dim3(2, M/64), 256, 0, stream>>>(
        x, nullptr, wsiH, wsiL, wsi_b, h, 1024);
    // K2: e_h, e_t
    gemm_mfma<0, false, false><<<dim3(2, M/64), 256, 0, stream>>>(
        h, nullptr, whH, whL, wh_b, e_h, 256);
    gemm_mfma<0, false, false><<<dim3(2, M/64), 256, 0, stream>>>(
        h, nullptr, wtH, wtL, wt_b, e_t, 256);
    // pack activations (hi only)
    pack_hi<<<1536, 256, 0, stream>>>(e_h, ehh, 0.0625f);
    pack_hi<<<1536, 256, 0, stream>>>(e_t, eth, 1.0f);
    // S1 / B1 / S2 / S3
    s1_gmax<<<384, 256, 0, stream>>>(ehh, eth, gmax16);
    b1_tau<<<M/256, 256, 0, stream>>>(gmax16, tau);
    hipMemsetAsync(cnt, 0, (size_t)M*sizeof(unsigned int), stream);
    s2_collect<<<384, 256, 0, stream>>>(ehh, eth, tau, cnt, cand);
    s3_tail<<<M/4, 256, 0, stream>>>(e_h, e_t, cnt, cand, e_Nh);
    // K5: out = relu((e_h+e_Nh)@w1+b1) + relu((e_h*e_Nh)@w2+b2)
    gemm_mfma<1, true, false><<<dim3(2, M/64), 256, 0, stream>>>(
        e_h, e_Nh, w1H, w1L, w1_b, out, 256);
    gemm_mfma<2, true, true><<<dim3(2, M/64), 256, 0, stream>>>(
        e_h, e_Nh, w2H, w2L, w2_b, out, 256);
}